// Round 14
// baseline (616.900 us; speedup 1.0000x reference)
//
#include <hip/hip_runtime.h>
#include <hip/hip_bf16.h>
#include <math.h>

#define B_SZ 4
#define CDIM 512
#define NPIX 4096
#define EPSN 1e-5f

typedef unsigned short u16;
typedef __attribute__((ext_vector_type(8))) short bf16x8;
typedef __attribute__((ext_vector_type(4))) float f32x4;
typedef __attribute__((ext_vector_type(16))) float f32x16;

#define MFMA_BF16 __builtin_amdgcn_mfma_f32_16x16x32_bf16
#define MFMA32    __builtin_amdgcn_mfma_f32_32x32x16_bf16

// async global->LDS DMA, 16B per lane; LDS dest = wave-uniform base + lane*16
#define GLD16(gp, lp) __builtin_amdgcn_global_load_lds( \
    (const __attribute__((address_space(1))) void*)(gp), \
    (__attribute__((address_space(3))) void*)(lp), 16, 0, 0)

static __device__ __forceinline__ float bf2f(u16 u) {
    return __uint_as_float(((unsigned)u) << 16);
}
static __device__ __forceinline__ u16 f2bf(float f) {
    unsigned u = __float_as_uint(f);
    unsigned r = (u + 0x7FFFu + ((u >> 16) & 1u)) >> 16;
    return (u16)r;
}
// packed square of a bf16x8 fragment, truncating round (bias < 2^-8 rel)
static __device__ __forceinline__ bf16x8 sq_bf16x8(bf16x8 a) {
    union { bf16x8 v; unsigned w[4]; } in, out;
    in.v = a;
    #pragma unroll
    for (int k = 0; k < 4; k++) {
        unsigned wl = in.w[k] << 16;
        unsigned wh = in.w[k] & 0xFFFF0000u;
        float sl = __uint_as_float(wl); sl *= sl;
        float sh = __uint_as_float(wh); sh *= sh;
        out.w[k] = (__float_as_uint(sh) & 0xFFFF0000u) | (__float_as_uint(sl) >> 16);
    }
    return out.v;
}

// ---------------------------------------------------------------------------
// transpose3: z selects source fp32 [CDIM][NPIX] -> XTz bf16 [NPIX][CDIM]
// ---------------------------------------------------------------------------
__global__ __launch_bounds__(256) void transpose3(const float* __restrict__ X0,
    const float* __restrict__ X1, const float* __restrict__ X2,
    u16* __restrict__ T0, u16* __restrict__ T1, u16* __restrict__ T2, size_t boff)
{
    const int z = blockIdx.z;
    const float* X = (z == 0 ? X0 : z == 1 ? X1 : X2) + boff;
    u16* XT = z == 0 ? T0 : z == 1 ? T1 : T2;

    __shared__ float T[64][65];
    const int t = threadIdx.x;
    const int n0 = blockIdx.x * 64, c0 = blockIdx.y * 64;
    #pragma unroll
    for (int p = 0; p < 4; p++) {
        int c_l = (t >> 4) + p * 16;
        int n_l = (t & 15) * 4;
        float4 v = *(const float4*)&X[(size_t)(c0 + c_l) * NPIX + n0 + n_l];
        T[c_l][n_l+0] = v.x; T[c_l][n_l+1] = v.y; T[c_l][n_l+2] = v.z; T[c_l][n_l+3] = v.w;
    }
    __syncthreads();
    #pragma unroll
    for (int p = 0; p < 4; p++) {
        int n_l = t >> 2;
        int cs  = (t & 3) * 4 + p * 16;
        ushort4 r;
        r.x = f2bf(T[cs+0][n_l]); r.y = f2bf(T[cs+1][n_l]);
        r.z = f2bf(T[cs+2][n_l]); r.w = f2bf(T[cs+3][n_l]);
        *(ushort4*)&XT[(size_t)(n0 + n_l) * CDIM + c0 + cs] = r;
    }
}

// ---------------------------------------------------------------------------
// conv3: z in {0,1,2}: D[o][n] = bias[o] + sum_c Wz[o][c]*XTz[n][c]
// z<2: store D^T to Yz=[n][CDIM] bf16 (FT/GT). z==2: store Hb=[CDIM][NPIX].
// ---------------------------------------------------------------------------
__global__ __launch_bounds__(256) void conv3(
    const u16* __restrict__ XT0, const u16* __restrict__ XT1, const u16* __restrict__ XT2,
    const float* __restrict__ W0, const float* __restrict__ W1, const float* __restrict__ W2,
    const float* __restrict__ b0, const float* __restrict__ b1, const float* __restrict__ b2,
    u16* __restrict__ Y0, u16* __restrict__ Y1, u16* __restrict__ Y2)
{
    const int z = blockIdx.z;
    const u16* XT = z == 0 ? XT0 : z == 1 ? XT1 : XT2;
    const float* W = z == 0 ? W0 : z == 1 ? W1 : W2;
    const float* bias = z == 0 ? b0 : z == 1 ? b1 : b2;

    const int t = threadIdx.x;
    const int lane = t & 63, wv = t >> 6;
    const int wr = wv >> 1, wc = wv & 1;
    const int n0 = blockIdx.x * 64;
    const int o0 = blockIdx.y * 64;
    const int g = lane >> 4, li = lane & 15;

    __shared__ short Aw[64][40];
    __shared__ short Bx[64][40];

    f32x4 acc[2][2] = {};
    const int srow = t >> 2, sseg = (t & 3) * 8;

    float4 w0 = *(const float4*)&W[(size_t)(o0 + srow) * CDIM + sseg];
    float4 w1 = *(const float4*)&W[(size_t)(o0 + srow) * CDIM + sseg + 4];
    bf16x8 bv = *(const bf16x8*)&XT[(size_t)(n0 + srow) * CDIM + sseg];

    for (int kb = 0; kb < CDIM; kb += 32) {
        bf16x8 wa;
        wa[0] = (short)f2bf(w0.x); wa[1] = (short)f2bf(w0.y);
        wa[2] = (short)f2bf(w0.z); wa[3] = (short)f2bf(w0.w);
        wa[4] = (short)f2bf(w1.x); wa[5] = (short)f2bf(w1.y);
        wa[6] = (short)f2bf(w1.z); wa[7] = (short)f2bf(w1.w);
        __syncthreads();
        *(bf16x8*)&Aw[srow][sseg] = wa;
        *(bf16x8*)&Bx[srow][sseg] = bv;
        if (kb + 32 < CDIM) {
            w0 = *(const float4*)&W[(size_t)(o0 + srow) * CDIM + kb + 32 + sseg];
            w1 = *(const float4*)&W[(size_t)(o0 + srow) * CDIM + kb + 32 + sseg + 4];
            bv = *(const bf16x8*)&XT[(size_t)(n0 + srow) * CDIM + kb + 32 + sseg];
        }
        __syncthreads();
        bf16x8 a[2], b[2];
        #pragma unroll
        for (int i = 0; i < 2; i++) a[i] = *(const bf16x8*)&Aw[wr*32 + i*16 + li][g*8];
        #pragma unroll
        for (int j = 0; j < 2; j++) b[j] = *(const bf16x8*)&Bx[wc*32 + j*16 + li][g*8];
        #pragma unroll
        for (int i = 0; i < 2; i++)
            #pragma unroll
            for (int j = 0; j < 2; j++)
                acc[i][j] = MFMA_BF16(a[i], b[j], acc[i][j], 0, 0, 0);
    }

    #pragma unroll
    for (int i = 0; i < 2; i++) {
        const int orow = o0 + wr*32 + i*16 + 4*g;
        float4 bs = *(const float4*)&bias[orow];
        #pragma unroll
        for (int j = 0; j < 2; j++) {
            const int ncol = n0 + wc*32 + j*16 + li;
            if (z < 2) {
                u16* Y = z == 0 ? Y0 : Y1;
                ushort4 r;
                r.x = f2bf(acc[i][j][0] + bs.x);
                r.y = f2bf(acc[i][j][1] + bs.y);
                r.z = f2bf(acc[i][j][2] + bs.z);
                r.w = f2bf(acc[i][j][3] + bs.w);
                *(ushort4*)&Y[(size_t)ncol * CDIM + orow] = r;
            } else {
                const float bb[4] = { bs.x, bs.y, bs.z, bs.w };
                #pragma unroll
                for (int r = 0; r < 4; r++)
                    Y2[(size_t)(orow + r) * NPIX + ncol] = f2bf(acc[i][j][r] + bb[r]);
            }
        }
    }
}

// ---------------------------------------------------------------------------
// norm2: z=0: Fn[n]=sqrt(sum FT[n][c]^2), rs[n]=0 ; z=1: Gn from GT
// ---------------------------------------------------------------------------
__global__ __launch_bounds__(256) void norm2(const u16* __restrict__ FT,
    const u16* __restrict__ GT, float* __restrict__ Fn, float* __restrict__ Gn,
    float* __restrict__ rs)
{
    const int z = blockIdx.y;
    const int n = blockIdx.x * 256 + threadIdx.x;
    const u16* row = (z ? GT : FT) + (size_t)n * CDIM;
    float s = 0.f;
    for (int c = 0; c < CDIM; c += 8) {
        bf16x8 v = *(const bf16x8*)&row[c];
        #pragma unroll
        for (int e = 0; e < 8; e++) { float f = bf2f((u16)v[e]); s += f * f; }
    }
    (z ? Gn : Fn)[n] = sqrtf(s);
    if (!z) rs[n] = 0.f;
}

// ---------------------------------------------------------------------------
// s_gemm128: S[nl][m] = bf16(relu(dot/((Fn+e)(Gn+e)) + 1)), + rowsum atomics.
// 128x128 tile, 4 waves (2x2 of 64x64), K-step 32, gld_lds DMA staging
// with source-side swizzle (unchanged from round 13).
// ---------------------------------------------------------------------------
__global__ __launch_bounds__(256) void s_gemm128(const u16* __restrict__ FT,
    const u16* __restrict__ GT, const float* __restrict__ Fn, const float* __restrict__ Gn,
    u16* __restrict__ S, float* __restrict__ rs, int strip_base, int swz)
{
    const int t = threadIdx.x;
    const int lane = t & 63, wv = t >> 6;
    const int wr = wv >> 1, wc = wv & 1;

    int mm, nn;
    if (swz) {            // (ns/128) % 8 == 0
        const int xk = blockIdx.x & 7, q = blockIdx.x >> 3;
        mm = q & 31;                      // NPIX/128 == 32
        nn = (q >> 5) * 8 + xk;
    } else {
        mm = blockIdx.x & 31;
        nn = blockIdx.x >> 5;
    }
    const int m0  = mm * 128;
    const int nl0 = nn * 128;
    const int ng0 = strip_base + nl0;
    const int g = lane >> 4, li = lane & 15;

    __shared__ short Cs[2][128][64];   // 32 KB total

    f32x4 acc[4][4] = {};

    const int lr = lane >> 3, lq = lane & 7;

    #define SG_STAGE(BUF, KB)                                                  \
    {                                                                          \
        _Pragma("unroll")                                                      \
        for (int ch = 0; ch < 4; ch++) {                                       \
            const int r0 = wv*32 + ch*8;                                       \
            const int r  = r0 + lr;                                            \
            const int c  = lq ^ (r & 7);                                       \
            const u16* gp = (c < 4)                                            \
                ? &FT[(size_t)(ng0 + r) * CDIM + (KB) + c*8]                   \
                : &GT[(size_t)(m0  + r) * CDIM + (KB) + (c-4)*8];              \
            GLD16(gp, &Cs[BUF][r0][0]);                                        \
        }                                                                      \
    }

    SG_STAGE(0, 0);
    __syncthreads();

    int buf = 0;
    for (int kb = 0; kb < CDIM; kb += 32) {
        if (kb + 32 < CDIM) SG_STAGE(buf ^ 1, kb + 32);
        bf16x8 a[4], b[4];
        #pragma unroll
        for (int i = 0; i < 4; i++) {
            const int row = wr*64 + i*16 + li;
            a[i] = *(const bf16x8*)&Cs[buf][row][(g ^ (row & 7)) * 8];
        }
        #pragma unroll
        for (int j = 0; j < 4; j++) {
            const int row = wc*64 + j*16 + li;
            b[j] = *(const bf16x8*)&Cs[buf][row][((4 + g) ^ (row & 7)) * 8];
        }
        #pragma unroll
        for (int i = 0; i < 4; i++)
            #pragma unroll
            for (int j = 0; j < 4; j++)
                acc[i][j] = MFMA_BF16(a[i], b[j], acc[i][j], 0, 0, 0);
        __syncthreads();
        buf ^= 1;
    }
    #undef SG_STAGE

    float gi[4];
    #pragma unroll
    for (int j = 0; j < 4; j++) gi[j] = 1.f / (Gn[m0 + wc*64 + j*16 + li] + EPSN);
    #pragma unroll
    for (int i = 0; i < 4; i++) {
        const int nl = nl0 + wr*64 + i*16 + 4*g;
        float4 fn4 = *(const float4*)&Fn[strip_base + nl];
        const float fi4[4] = { 1.f/(fn4.x + EPSN), 1.f/(fn4.y + EPSN),
                               1.f/(fn4.z + EPSN), 1.f/(fn4.w + EPSN) };
        float ps[4] = {0.f, 0.f, 0.f, 0.f};
        #pragma unroll
        for (int j = 0; j < 4; j++) {
            const int m = m0 + wc*64 + j*16 + li;
            #pragma unroll
            for (int r = 0; r < 4; r++) {
                float v = fmaxf(acc[i][j][r] * fi4[r] * gi[j] + 1.f, 0.f);
                u16 hv = f2bf(v);
                S[(size_t)(nl + r) * NPIX + m] = hv;
                ps[r] += bf2f(hv);
            }
        }
        #pragma unroll
        for (int r = 0; r < 4; r++) {
            float p = ps[r];
            p += __shfl_xor(p, 1);
            p += __shfl_xor(p, 2);
            p += __shfl_xor(p, 4);
            p += __shfl_xor(p, 8);
            if (li == 0) atomicAdd(&rs[strip_base + nl + r], p);
        }
    }
}

// ---------------------------------------------------------------------------
// pv64x128: mean/msq via MFMA 32x32x16 (dual chains, H^2 in-register).
// RETILED: 64c x 128n per block, 512 threads / 8 waves (2wr x 4wc of 32x32).
// Per-dispatch logical L2/L3 traffic drops 512->384 MB (the r9-r13 plateau
// at ~8.7 TB/s says cache-BW is the binding constraint, not scheduling).
// gld_lds DMA staging (3 chunks/wave/K-step) with source-side 8-slot XOR
// swizzle; double-buffered 48 KB LDS; grid 256 blocks + XCD swizzle.
// ---------------------------------------------------------------------------
__global__ __launch_bounds__(512) void pv64x128(const u16* __restrict__ Hb,
    const u16* __restrict__ Sb, const float* __restrict__ rs,
    const float* __restrict__ content_b, const float* __restrict__ mu,
    const float* __restrict__ isd, float* __restrict__ out_b, int strip_base, int swz)
{
    const int t = threadIdx.x;
    const int lane = t & 63, wv = t >> 6;       // 8 waves
    const int wr = wv >> 2, wc = wv & 3;        // 2 x 4
    const int l31 = lane & 31, h = lane >> 5;

    int c_t, n_t;
    if (swz) {      // (ns/128) % 8 == 0
        const int xk = blockIdx.x & 7, q = blockIdx.x >> 3;
        c_t = q & 7;                            // CDIM/64 == 8
        n_t = (q >> 3) * 8 + xk;
    } else {
        c_t = blockIdx.x & 7;
        n_t = blockIdx.x >> 3;
    }
    const int c0  = c_t * 64;
    const int nl0 = n_t * 128;

    __shared__ short AH[2][64][64];    // H rows, 16 KB
    __shared__ short SS[2][128][64];   // S rows, 32 KB

    f32x16 am = {}, aq = {};

    // staging: 24 x 1KB chunks (8 H + 16 S), 3 per wave; chunk = 8 rows x 128B;
    // lane -> row r0+(l>>3), phys slot l&7; global col-slot = (l&7) ^ (r&7)
    const int lr = lane >> 3, lq = lane & 7;

    #define PV_STAGE(BUF, KB)                                                  \
    {                                                                          \
        _Pragma("unroll")                                                      \
        for (int ch = 0; ch < 3; ch++) {                                       \
            const int id = wv*3 + ch;                                          \
            if (id < 8) {                                                      \
                const int r0 = id*8, r = r0 + lr, c = lq ^ (r & 7);            \
                GLD16(&Hb[(size_t)(c0 + r) * NPIX + (KB) + c*8],               \
                      &AH[BUF][r0][0]);                                        \
            } else {                                                           \
                const int r0 = (id-8)*8, r = r0 + lr, c = lq ^ (r & 7);        \
                GLD16(&Sb[(size_t)(nl0 + r) * NPIX + (KB) + c*8],              \
                      &SS[BUF][r0][0]);                                        \
            }                                                                  \
        }                                                                      \
    }

    const int ra = wr*32 + l31;        // 0..63  (H row)
    const int rb = wc*32 + l31;        // 0..127 (S row)

    PV_STAGE(0, 0);
    __syncthreads();

    int buf = 0;
    for (int kb = 0; kb < NPIX; kb += 64) {
        if (kb + 64 < NPIX) PV_STAGE(buf ^ 1, kb + 64);
        const short* rpa = &AH[buf][ra][0];
        const short* rpb = &SS[buf][rb][0];
        #pragma unroll
        for (int ks = 0; ks < 4; ks++) {
            bf16x8 a  = *(const bf16x8*)&rpa[(((ks*2 + h) ^ (ra & 7)) * 8)];
            bf16x8 b  = *(const bf16x8*)&rpb[(((ks*2 + h) ^ (rb & 7)) * 8)];
            bf16x8 a2 = sq_bf16x8(a);
            am = MFMA32(a,  b, am, 0, 0, 0);
            aq = MFMA32(a2, b, aq, 0, 0, 0);
        }
        __syncthreads();
        buf ^= 1;
    }
    #undef PV_STAGE

    // C layout (32x32): col = lane&31 (n), row = (reg&3) + 8*(reg>>2) + 4*h (c)
    const int n = strip_base + nl0 + wc*32 + l31;
    const float inv = 1.f / (rs[n] + EPSN);
    #pragma unroll
    for (int qd = 0; qd < 4; qd++) {
        const int cb = c0 + wr*32 + 8*qd + 4*h;
        float4 mu4 = *(const float4*)&mu[cb];
        float4 is4 = *(const float4*)&isd[cb];
        const float muA[4] = { mu4.x, mu4.y, mu4.z, mu4.w };
        const float isA[4] = { is4.x, is4.y, is4.z, is4.w };
        #pragma unroll
        for (int r2 = 0; r2 < 4; r2++) {
            const int reg = qd*4 + r2;
            float mean = am[reg] * inv;
            float msq  = aq[reg] * inv;
            float sd   = sqrtf(fmaxf(msq - mean*mean, 0.f));
            float cv   = content_b[(size_t)(cb + r2) * NPIX + n];
            out_b[(size_t)(cb + r2) * NPIX + n] = sd * (cv - muA[r2]) * isA[r2] + mean;
        }
    }
}

// ---------------------------------------------------------------------------
// content_stats: per (b,c) mean and 1/std (unbiased var, +1e-5), fp32 input
// ---------------------------------------------------------------------------
__global__ __launch_bounds__(256) void content_stats(const float* __restrict__ x,
    float* __restrict__ mu, float* __restrict__ isd)
{
    const int bc = blockIdx.x;
    const int tid = threadIdx.x;
    const float* row = x + (size_t)bc * NPIX;
    float s = 0.f, s2 = 0.f;
    for (int i = tid * 4; i < NPIX; i += 256 * 4) {
        float4 v = *(const float4*)&row[i];
        s  += v.x + v.y + v.z + v.w;
        s2 += v.x*v.x + v.y*v.y + v.z*v.z + v.w*v.w;
    }
    __shared__ float r1[256], r2[256];
    r1[tid] = s; r2[tid] = s2; __syncthreads();
    for (int st = 128; st; st >>= 1) {
        if (tid < st) { r1[tid] += r1[tid+st]; r2[tid] += r2[tid+st]; }
        __syncthreads();
    }
    if (tid == 0) {
        float m = r1[0] / NPIX;
        float var = (r2[0] - (float)NPIX * m * m) / (float)(NPIX - 1);
        mu[bc]  = m;
        isd[bc] = rsqrtf(var + 1e-5f);
    }
}

// ---------------------------------------------------------------------------
extern "C" void kernel_launch(void* const* d_in, const int* in_sizes, int n_in,
                              void* d_out, int out_size, void* d_ws, size_t ws_size,
                              hipStream_t stream)
{
    const float* content     = (const float*)d_in[0];
    const float* style       = (const float*)d_in[1];
    const float* content_key = (const float*)d_in[2];
    const float* style_key   = (const float*)d_in[3];
    const float* Wf  = (const float*)d_in[4];
    const float* bf_ = (const float*)d_in[5];
    const float* Wg  = (const float*)d_in[6];
    const float* bg  = (const float*)d_in[7];
    const float* Wh  = (const float*)d_in[8];
    const float* bh  = (const float*)d_in[9];
    float* out = (float*)d_out;

    const size_t TB = (size_t)CDIM * NPIX;   // elems per batch-tensor

    const size_t tail_bytes = ((size_t)NPIX * 3 + 2 * (size_t)B_SZ * CDIM) * 4 + 256;
    const size_t fixed = 6 * TB * 2 + tail_bytes;
    int ns = 512;
    for (int cand = NPIX; cand >= 512; cand >>= 1) {
        if (fixed + (size_t)NPIX * cand * 2 <= ws_size) { ns = cand; break; }
    }

    u16* FT  = (u16*)d_ws;                   // [NPIX][CDIM]
    u16* GT  = FT + TB;                      // [NPIX][CDIM]
    u16* Hb  = GT + TB;                      // [CDIM][NPIX]
    u16* XT0 = Hb + TB;                      // [NPIX][CDIM]
    u16* XT1 = XT0 + TB;
    u16* XT2 = XT1 + TB;
    u16* Sb  = XT2 + TB;                     // [ns][NPIX]
    float* Fn  = (float*)(Sb + (size_t)NPIX * ns);
    float* Gn  = Fn + NPIX;
    float* rsb = Gn + NPIX;
    float* mu  = rsb + NPIX;
    float* isd = mu + (size_t)B_SZ * CDIM;

    content_stats<<<B_SZ * CDIM, 256, 0, stream>>>(content, mu, isd);

    const int sg_swz = ((ns / 128) % 8 == 0) ? 1 : 0;
    const int sg_blocks = (NPIX / 128) * (ns / 128);
    const int pv_swz = ((ns / 128) % 8 == 0) ? 1 : 0;
    const int pv_blocks = 8 * (ns / 128);

    for (int b = 0; b < B_SZ; b++) {
        const size_t bo = (size_t)b * TB;

        transpose3<<<dim3(NPIX/64, CDIM/64, 3), 256, 0, stream>>>(
                content_key, style_key, style, XT0, XT1, XT2, bo);

        conv3<<<dim3(NPIX/64, CDIM/64, 3), 256, 0, stream>>>(
                XT0, XT1, XT2, Wf, Wg, Wh, bf_, bg, bh, FT, GT, Hb);

        norm2<<<dim3(NPIX/256, 2), 256, 0, stream>>>(FT, GT, Fn, Gn, rsb);

        for (int s0 = 0; s0 < NPIX; s0 += ns) {
            s_gemm128<<<sg_blocks, 256, 0, stream>>>(FT, GT, Fn, Gn, Sb, rsb, s0, sg_swz);
            pv64x128<<<pv_blocks, 512, 0, stream>>>(Hb, Sb, rsb,
                    content + bo, mu + b*CDIM, isd + b*CDIM, out + bo, s0, pv_swz);
        }
    }
}

// Round 15
// 428.045 us; speedup vs baseline: 1.4412x; 1.4412x over previous
//
#include <hip/hip_runtime.h>
#include <hip/hip_bf16.h>
#include <math.h>

#define B_SZ 4
#define CDIM 512
#define NPIX 4096
#define EPSN 1e-5f

typedef unsigned short u16;
typedef __attribute__((ext_vector_type(8))) short bf16x8;
typedef __attribute__((ext_vector_type(4))) float f32x4;
typedef __attribute__((ext_vector_type(16))) float f32x16;

#define MFMA_BF16 __builtin_amdgcn_mfma_f32_16x16x32_bf16
#define MFMA32    __builtin_amdgcn_mfma_f32_32x32x16_bf16

// async global->LDS DMA, 16B per lane; LDS dest = wave-uniform base + lane*16
#define GLD16(gp, lp) __builtin_amdgcn_global_load_lds( \
    (const __attribute__((address_space(1))) void*)(gp), \
    (__attribute__((address_space(3))) void*)(lp), 16, 0, 0)

static __device__ __forceinline__ float bf2f(u16 u) {
    return __uint_as_float(((unsigned)u) << 16);
}
static __device__ __forceinline__ u16 f2bf(float f) {
    unsigned u = __float_as_uint(f);
    unsigned r = (u + 0x7FFFu + ((u >> 16) & 1u)) >> 16;
    return (u16)r;
}
// packed square of a bf16x8 fragment, truncating round (bias < 2^-8 rel)
static __device__ __forceinline__ bf16x8 sq_bf16x8(bf16x8 a) {
    union { bf16x8 v; unsigned w[4]; } in, out;
    in.v = a;
    #pragma unroll
    for (int k = 0; k < 4; k++) {
        unsigned wl = in.w[k] << 16;
        unsigned wh = in.w[k] & 0xFFFF0000u;
        float sl = __uint_as_float(wl); sl *= sl;
        float sh = __uint_as_float(wh); sh *= sh;
        out.w[k] = (__float_as_uint(sh) & 0xFFFF0000u) | (__float_as_uint(sl) >> 16);
    }
    return out.v;
}

// ---------------------------------------------------------------------------
// transpose3b: z = gb*3 + which; source fp32 [CDIM][NPIX] (global batch
// bg0+gb) -> XT slab entry z, bf16 [NPIX][CDIM].
// ---------------------------------------------------------------------------
__global__ __launch_bounds__(256) void transpose3b(const float* __restrict__ X0,
    const float* __restrict__ X1, const float* __restrict__ X2,
    u16* __restrict__ XTbase, int bg0)
{
    const int z = blockIdx.z;
    const int gb = z / 3, which = z % 3;
    const size_t TBe = (size_t)CDIM * NPIX;
    const float* X = (which == 0 ? X0 : which == 1 ? X1 : X2) + (size_t)(bg0 + gb) * TBe;
    u16* XT = XTbase + (size_t)z * TBe;

    __shared__ float T[64][65];
    const int t = threadIdx.x;
    const int n0 = blockIdx.x * 64, c0 = blockIdx.y * 64;
    #pragma unroll
    for (int p = 0; p < 4; p++) {
        int c_l = (t >> 4) + p * 16;
        int n_l = (t & 15) * 4;
        float4 v = *(const float4*)&X[(size_t)(c0 + c_l) * NPIX + n0 + n_l];
        T[c_l][n_l+0] = v.x; T[c_l][n_l+1] = v.y; T[c_l][n_l+2] = v.z; T[c_l][n_l+3] = v.w;
    }
    __syncthreads();
    #pragma unroll
    for (int p = 0; p < 4; p++) {
        int n_l = t >> 2;
        int cs  = (t & 3) * 4 + p * 16;
        ushort4 r;
        r.x = f2bf(T[cs+0][n_l]); r.y = f2bf(T[cs+1][n_l]);
        r.z = f2bf(T[cs+2][n_l]); r.w = f2bf(T[cs+3][n_l]);
        *(ushort4*)&XT[(size_t)(n0 + n_l) * CDIM + c0 + cs] = r;
    }
}

// ---------------------------------------------------------------------------
// conv3b: z = gb*3 + which. D[o][n] = bias[o] + sum_c W[o][c]*XT[n][c].
// which<2: store D^T to (FT|GT)+gb*TB ([n][CDIM]); which==2: Hb+gb*TB.
// ---------------------------------------------------------------------------
__global__ __launch_bounds__(256) void conv3b(const u16* __restrict__ XTbase,
    const float* __restrict__ W0, const float* __restrict__ W1, const float* __restrict__ W2,
    const float* __restrict__ b0, const float* __restrict__ b1, const float* __restrict__ b2,
    u16* __restrict__ FTb, u16* __restrict__ GTb, u16* __restrict__ Hbb)
{
    const int z = blockIdx.z;
    const int gb = z / 3, which = z % 3;
    const size_t TBe = (size_t)CDIM * NPIX;
    const u16* XT = XTbase + (size_t)z * TBe;
    const float* W = which == 0 ? W0 : which == 1 ? W1 : W2;
    const float* bias = which == 0 ? b0 : which == 1 ? b1 : b2;

    const int t = threadIdx.x;
    const int lane = t & 63, wv = t >> 6;
    const int wr = wv >> 1, wc = wv & 1;
    const int n0 = blockIdx.x * 64;
    const int o0 = blockIdx.y * 64;
    const int g = lane >> 4, li = lane & 15;

    __shared__ short Aw[64][40];
    __shared__ short Bx[64][40];

    f32x4 acc[2][2] = {};
    const int srow = t >> 2, sseg = (t & 3) * 8;

    float4 w0 = *(const float4*)&W[(size_t)(o0 + srow) * CDIM + sseg];
    float4 w1 = *(const float4*)&W[(size_t)(o0 + srow) * CDIM + sseg + 4];
    bf16x8 bv = *(const bf16x8*)&XT[(size_t)(n0 + srow) * CDIM + sseg];

    for (int kb = 0; kb < CDIM; kb += 32) {
        bf16x8 wa;
        wa[0] = (short)f2bf(w0.x); wa[1] = (short)f2bf(w0.y);
        wa[2] = (short)f2bf(w0.z); wa[3] = (short)f2bf(w0.w);
        wa[4] = (short)f2bf(w1.x); wa[5] = (short)f2bf(w1.y);
        wa[6] = (short)f2bf(w1.z); wa[7] = (short)f2bf(w1.w);
        __syncthreads();
        *(bf16x8*)&Aw[srow][sseg] = wa;
        *(bf16x8*)&Bx[srow][sseg] = bv;
        if (kb + 32 < CDIM) {
            w0 = *(const float4*)&W[(size_t)(o0 + srow) * CDIM + kb + 32 + sseg];
            w1 = *(const float4*)&W[(size_t)(o0 + srow) * CDIM + kb + 32 + sseg + 4];
            bv = *(const bf16x8*)&XT[(size_t)(n0 + srow) * CDIM + kb + 32 + sseg];
        }
        __syncthreads();
        bf16x8 a[2], b[2];
        #pragma unroll
        for (int i = 0; i < 2; i++) a[i] = *(const bf16x8*)&Aw[wr*32 + i*16 + li][g*8];
        #pragma unroll
        for (int j = 0; j < 2; j++) b[j] = *(const bf16x8*)&Bx[wc*32 + j*16 + li][g*8];
        #pragma unroll
        for (int i = 0; i < 2; i++)
            #pragma unroll
            for (int j = 0; j < 2; j++)
                acc[i][j] = MFMA_BF16(a[i], b[j], acc[i][j], 0, 0, 0);
    }

    #pragma unroll
    for (int i = 0; i < 2; i++) {
        const int orow = o0 + wr*32 + i*16 + 4*g;
        float4 bs = *(const float4*)&bias[orow];
        #pragma unroll
        for (int j = 0; j < 2; j++) {
            const int ncol = n0 + wc*32 + j*16 + li;
            if (which < 2) {
                u16* Y = (which == 0 ? FTb : GTb) + (size_t)gb * TBe;
                ushort4 r;
                r.x = f2bf(acc[i][j][0] + bs.x);
                r.y = f2bf(acc[i][j][1] + bs.y);
                r.z = f2bf(acc[i][j][2] + bs.z);
                r.w = f2bf(acc[i][j][3] + bs.w);
                *(ushort4*)&Y[(size_t)ncol * CDIM + orow] = r;
            } else {
                u16* Y2 = Hbb + (size_t)gb * TBe;
                const float bb[4] = { bs.x, bs.y, bs.z, bs.w };
                #pragma unroll
                for (int r = 0; r < 4; r++)
                    Y2[(size_t)(orow + r) * NPIX + ncol] = f2bf(acc[i][j][r] + bb[r]);
            }
        }
    }
}

// ---------------------------------------------------------------------------
// norm2b: blockIdx.y = gb*2 + z. z=0: Fn[gb][n], rs[gb][n]=0 ; z=1: Gn[gb][n]
// ---------------------------------------------------------------------------
__global__ __launch_bounds__(256) void norm2b(const u16* __restrict__ FT,
    const u16* __restrict__ GT, float* __restrict__ Fn, float* __restrict__ Gn,
    float* __restrict__ rs)
{
    const int gb = blockIdx.y >> 1, z = blockIdx.y & 1;
    const size_t TBe = (size_t)CDIM * NPIX;
    const int n = blockIdx.x * 256 + threadIdx.x;
    const u16* row = ((z ? GT : FT) + (size_t)gb * TBe) + (size_t)n * CDIM;
    float s = 0.f;
    for (int c = 0; c < CDIM; c += 8) {
        bf16x8 v = *(const bf16x8*)&row[c];
        #pragma unroll
        for (int e = 0; e < 8; e++) { float f = bf2f((u16)v[e]); s += f * f; }
    }
    ((z ? Gn : Fn) + (size_t)gb * NPIX)[n] = sqrtf(s);
    if (!z) rs[(size_t)gb * NPIX + n] = 0.f;
}

// ---------------------------------------------------------------------------
// s_gemm128: S[nl][m] = bf16(relu(dot/((Fn+e)(Gn+e)) + 1)), + rowsum atomics.
// 128x128 tile, 4 waves (2x2 of 64x64), K-step 32, gld_lds DMA staging with
// source-side swizzle. blockIdx.y = group-local batch gb.
// ---------------------------------------------------------------------------
__global__ __launch_bounds__(256) void s_gemm128(const u16* __restrict__ FTb,
    const u16* __restrict__ GTb, const float* __restrict__ Fnb, const float* __restrict__ Gnb,
    u16* __restrict__ Sbase, float* __restrict__ rsb, int strip_base, int swz,
    size_t s_stride)
{
    const int gb = blockIdx.y;
    const size_t TBe = (size_t)CDIM * NPIX;
    const u16* FT = FTb + (size_t)gb * TBe;
    const u16* GT = GTb + (size_t)gb * TBe;
    const float* Fn = Fnb + (size_t)gb * NPIX;
    const float* Gn = Gnb + (size_t)gb * NPIX;
    u16* S = Sbase + (size_t)gb * s_stride;
    float* rs = rsb + (size_t)gb * NPIX;

    const int t = threadIdx.x;
    const int lane = t & 63, wv = t >> 6;
    const int wr = wv >> 1, wc = wv & 1;

    int mm, nn;
    if (swz) {            // (ns/128) % 8 == 0
        const int xk = blockIdx.x & 7, q = blockIdx.x >> 3;
        mm = q & 31;                      // NPIX/128 == 32
        nn = (q >> 5) * 8 + xk;
    } else {
        mm = blockIdx.x & 31;
        nn = blockIdx.x >> 5;
    }
    const int m0  = mm * 128;
    const int nl0 = nn * 128;
    const int ng0 = strip_base + nl0;
    const int g = lane >> 4, li = lane & 15;

    __shared__ short Cs[2][128][64];   // 32 KB total

    f32x4 acc[4][4] = {};

    const int lr = lane >> 3, lq = lane & 7;

    #define SG_STAGE(BUF, KB)                                                  \
    {                                                                          \
        _Pragma("unroll")                                                      \
        for (int ch = 0; ch < 4; ch++) {                                       \
            const int r0 = wv*32 + ch*8;                                       \
            const int r  = r0 + lr;                                            \
            const int c  = lq ^ (r & 7);                                       \
            const u16* gp = (c < 4)                                            \
                ? &FT[(size_t)(ng0 + r) * CDIM + (KB) + c*8]                   \
                : &GT[(size_t)(m0  + r) * CDIM + (KB) + (c-4)*8];              \
            GLD16(gp, &Cs[BUF][r0][0]);                                        \
        }                                                                      \
    }

    SG_STAGE(0, 0);
    __syncthreads();

    int buf = 0;
    for (int kb = 0; kb < CDIM; kb += 32) {
        if (kb + 32 < CDIM) SG_STAGE(buf ^ 1, kb + 32);
        bf16x8 a[4], b[4];
        #pragma unroll
        for (int i = 0; i < 4; i++) {
            const int row = wr*64 + i*16 + li;
            a[i] = *(const bf16x8*)&Cs[buf][row][(g ^ (row & 7)) * 8];
        }
        #pragma unroll
        for (int j = 0; j < 4; j++) {
            const int row = wc*64 + j*16 + li;
            b[j] = *(const bf16x8*)&Cs[buf][row][((4 + g) ^ (row & 7)) * 8];
        }
        #pragma unroll
        for (int i = 0; i < 4; i++)
            #pragma unroll
            for (int j = 0; j < 4; j++)
                acc[i][j] = MFMA_BF16(a[i], b[j], acc[i][j], 0, 0, 0);
        __syncthreads();
        buf ^= 1;
    }
    #undef SG_STAGE

    float gi[4];
    #pragma unroll
    for (int j = 0; j < 4; j++) gi[j] = 1.f / (Gn[m0 + wc*64 + j*16 + li] + EPSN);
    #pragma unroll
    for (int i = 0; i < 4; i++) {
        const int nl = nl0 + wr*64 + i*16 + 4*g;
        float4 fn4 = *(const float4*)&Fn[strip_base + nl];
        const float fi4[4] = { 1.f/(fn4.x + EPSN), 1.f/(fn4.y + EPSN),
                               1.f/(fn4.z + EPSN), 1.f/(fn4.w + EPSN) };
        float ps[4] = {0.f, 0.f, 0.f, 0.f};
        #pragma unroll
        for (int j = 0; j < 4; j++) {
            const int m = m0 + wc*64 + j*16 + li;
            #pragma unroll
            for (int r = 0; r < 4; r++) {
                float v = fmaxf(acc[i][j][r] * fi4[r] * gi[j] + 1.f, 0.f);
                u16 hv = f2bf(v);
                S[(size_t)(nl + r) * NPIX + m] = hv;
                ps[r] += bf2f(hv);
            }
        }
        #pragma unroll
        for (int r = 0; r < 4; r++) {
            float p = ps[r];
            p += __shfl_xor(p, 1);
            p += __shfl_xor(p, 2);
            p += __shfl_xor(p, 4);
            p += __shfl_xor(p, 8);
            if (li == 0) atomicAdd(&rs[strip_base + nl + r], p);
        }
    }
}

// ---------------------------------------------------------------------------
// pv64: (round-13 structure, best measured) mean/msq via MFMA 32x32x16,
// 64c x 64n tile, 4 waves, K-step 64, gld_lds DMA + 16-slot source-side
// swizzle, 0 bank conflicts. blockIdx.y = group-local batch gb — batching
// lifts resident blocks/CU from 2 to ~5 (LDS-capped), the r14 lesson that
// block-level TLP, not intra-block scheduling, hides the L2/L3 latency.
// ---------------------------------------------------------------------------
__global__ __launch_bounds__(256) void pv64(const u16* __restrict__ Hbb,
    const u16* __restrict__ Sbase, const float* __restrict__ rsb,
    const float* __restrict__ content, const float* __restrict__ mub,
    const float* __restrict__ isdb, float* __restrict__ out, int strip_base,
    int bg0, size_t s_stride)
{
    const int gb = blockIdx.y;
    const size_t TBe = (size_t)CDIM * NPIX;
    const u16* Hb = Hbb + (size_t)gb * TBe;
    const u16* Sb = Sbase + (size_t)gb * s_stride;
    const float* rs = rsb + (size_t)gb * NPIX;
    const float* content_b = content + (size_t)(bg0 + gb) * TBe;
    const float* mu  = mub  + (size_t)(bg0 + gb) * CDIM;
    const float* isd = isdb + (size_t)(bg0 + gb) * CDIM;
    float* out_b = out + (size_t)(bg0 + gb) * TBe;

    const int t = threadIdx.x;
    const int lane = t & 63, wv = t >> 6;
    const int wr = wv >> 1, wc = wv & 1;
    const int l31 = lane & 31, h = lane >> 5;

    const int xk = blockIdx.x & 7, q = blockIdx.x >> 3;
    const int c0  = (q & 7) * 64;               // CDIM/64 == 8
    const int nl0 = ((q >> 3) * 8 + xk) * 64;   // (ns/64) % 8 == 0

    __shared__ short AS[2][64][128];            // 32 KB total

    f32x16 am = {}, aq = {};

    const int lr = lane >> 4, lq = lane & 15;

    #define PV_STAGE(BUF, KB)                                                  \
    {                                                                          \
        _Pragma("unroll")                                                      \
        for (int ch = 0; ch < 4; ch++) {                                       \
            const int r0 = wv*16 + ch*4;                                       \
            const int r  = r0 + lr;                                            \
            const int c  = lq ^ (r & 15);                                      \
            const u16* gp = (c < 8)                                            \
                ? &Hb[(size_t)(c0  + r) * NPIX + (KB) + c*8]                   \
                : &Sb[(size_t)(nl0 + r) * NPIX + (KB) + (c-8)*8];              \
            GLD16(gp, &AS[BUF][r0][0]);                                        \
        }                                                                      \
    }

    const int ra = wr*32 + l31, rb = wc*32 + l31;
    const int swa = (ra & 15) << 4, swb = (rb & 15) << 4;   // byte XOR masks

    PV_STAGE(0, 0);
    __syncthreads();

    int buf = 0;
    for (int kb = 0; kb < NPIX; kb += 64) {
        if (kb + 64 < NPIX) PV_STAGE(buf ^ 1, kb + 64);
        const short* rpa = &AS[buf][ra][0];
        const short* rpb = &AS[buf][rb][0];
        #pragma unroll
        for (int ks = 0; ks < 4; ks++) {
            bf16x8 a  = *(const bf16x8*)&rpa[((ks*32 + h*16      ) ^ swa) >> 1];
            bf16x8 b  = *(const bf16x8*)&rpb[((ks*32 + h*16 + 128) ^ swb) >> 1];
            bf16x8 a2 = sq_bf16x8(a);
            am = MFMA32(a,  b, am, 0, 0, 0);
            aq = MFMA32(a2, b, aq, 0, 0, 0);
        }
        __syncthreads();
        buf ^= 1;
    }
    #undef PV_STAGE

    // C layout (32x32): col = lane&31 (n), row = (reg&3) + 8*(reg>>2) + 4*h (c)
    const int n = strip_base + nl0 + wc*32 + l31;
    const float inv = 1.f / (rs[n] + EPSN);
    #pragma unroll
    for (int qd = 0; qd < 4; qd++) {
        const int cb = c0 + wr*32 + 8*qd + 4*h;
        float4 mu4 = *(const float4*)&mu[cb];
        float4 is4 = *(const float4*)&isd[cb];
        const float muA[4] = { mu4.x, mu4.y, mu4.z, mu4.w };
        const float isA[4] = { is4.x, is4.y, is4.z, is4.w };
        #pragma unroll
        for (int r2 = 0; r2 < 4; r2++) {
            const int reg = qd*4 + r2;
            float mean = am[reg] * inv;
            float msq  = aq[reg] * inv;
            float sd   = sqrtf(fmaxf(msq - mean*mean, 0.f));
            float cv   = content_b[(size_t)(cb + r2) * NPIX + n];
            out_b[(size_t)(cb + r2) * NPIX + n] = sd * (cv - muA[r2]) * isA[r2] + mean;
        }
    }
}

// ---------------------------------------------------------------------------
// content_stats: per (b,c) mean and 1/std (unbiased var, +1e-5), fp32 input
// ---------------------------------------------------------------------------
__global__ __launch_bounds__(256) void content_stats(const float* __restrict__ x,
    float* __restrict__ mu, float* __restrict__ isd)
{
    const int bc = blockIdx.x;
    const int tid = threadIdx.x;
    const float* row = x + (size_t)bc * NPIX;
    float s = 0.f, s2 = 0.f;
    for (int i = tid * 4; i < NPIX; i += 256 * 4) {
        float4 v = *(const float4*)&row[i];
        s  += v.x + v.y + v.z + v.w;
        s2 += v.x*v.x + v.y*v.y + v.z*v.z + v.w*v.w;
    }
    __shared__ float r1[256], r2[256];
    r1[tid] = s; r2[tid] = s2; __syncthreads();
    for (int st = 128; st; st >>= 1) {
        if (tid < st) { r1[tid] += r1[tid+st]; r2[tid] += r2[tid+st]; }
        __syncthreads();
    }
    if (tid == 0) {
        float m = r1[0] / NPIX;
        float var = (r2[0] - (float)NPIX * m * m) / (float)(NPIX - 1);
        mu[bc]  = m;
        isd[bc] = rsqrtf(var + 1e-5f);
    }
}

// ---------------------------------------------------------------------------
extern "C" void kernel_launch(void* const* d_in, const int* in_sizes, int n_in,
                              void* d_out, int out_size, void* d_ws, size_t ws_size,
                              hipStream_t stream)
{
    const float* content     = (const float*)d_in[0];
    const float* style       = (const float*)d_in[1];
    const float* content_key = (const float*)d_in[2];
    const float* style_key   = (const float*)d_in[3];
    const float* Wf  = (const float*)d_in[4];
    const float* bf_ = (const float*)d_in[5];
    const float* Wg  = (const float*)d_in[6];
    const float* bg  = (const float*)d_in[7];
    const float* Wh  = (const float*)d_in[8];
    const float* bh  = (const float*)d_in[9];
    float* out = (float*)d_out;

    const size_t TB = (size_t)CDIM * NPIX;   // elems per batch-tensor
    const size_t tail_bytes = (3 * (size_t)B_SZ * NPIX + 2 * (size_t)B_SZ * CDIM) * 4 + 256;

    // choose (nb, ns): bytes = nb*(6*TB + NPIX*ns)*2 + tail
    int nb = 1, ns = 512;
    {
        const int nbc[5] = {4, 2, 4, 2, 1};
        const int nsc[5] = {4096, 4096, 2048, 2048, 4096};
        bool found = false;
        for (int i = 0; i < 5; i++) {
            size_t need = (size_t)nbc[i] * (6 * TB + (size_t)NPIX * nsc[i]) * 2 + tail_bytes;
            if (need <= ws_size) { nb = nbc[i]; ns = nsc[i]; found = true; break; }
        }
        if (!found) {
            nb = 1;
            for (int cand = 2048; cand >= 512; cand >>= 1) {
                size_t need = (6 * TB + (size_t)NPIX * cand) * 2 + tail_bytes;
                if (need <= ws_size) { ns = cand; break; }
            }
        }
    }
    const size_t s_stride = (size_t)NPIX * ns;   // elems per batch S strip

    u16* FT  = (u16*)d_ws;                   // nb x [NPIX][CDIM]
    u16* GT  = FT + (size_t)nb * TB;
    u16* Hb  = GT + (size_t)nb * TB;         // nb x [CDIM][NPIX]
    u16* XT  = Hb + (size_t)nb * TB;         // nb*3 x [NPIX][CDIM]
    u16* Sb  = XT + (size_t)nb * 3 * TB;     // nb x [ns][NPIX]
    float* Fn  = (float*)(Sb + (size_t)nb * s_stride);
    float* Gn  = Fn + (size_t)B_SZ * NPIX;
    float* rsb = Gn + (size_t)B_SZ * NPIX;
    float* mu  = rsb + (size_t)B_SZ * NPIX;
    float* isd = mu + (size_t)B_SZ * CDIM;

    content_stats<<<B_SZ * CDIM, 256, 0, stream>>>(content, mu, isd);

    const int sg_swz = ((ns / 128) % 8 == 0) ? 1 : 0;
    const int sg_blocks = (NPIX / 128) * (ns / 128);
    const int pv_blocks = 8 * (ns / 64);

    for (int bg0 = 0; bg0 < B_SZ; bg0 += nb) {
        const int g = (bg0 + nb <= B_SZ) ? nb : (B_SZ - bg0);

        transpose3b<<<dim3(NPIX/64, CDIM/64, 3*g), 256, 0, stream>>>(
                content_key, style_key, style, XT, bg0);

        conv3b<<<dim3(NPIX/64, CDIM/64, 3*g), 256, 0, stream>>>(
                XT, Wf, Wg, Wh, bf_, bg, bh, FT, GT, Hb);

        norm2b<<<dim3(NPIX/256, 2*g), 256, 0, stream>>>(FT, GT, Fn, Gn, rsb);

        for (int s0 = 0; s0 < NPIX; s0 += ns) {
            s_gemm128<<<dim3(sg_blocks, g), 256, 0, stream>>>(FT, GT, Fn, Gn,
                    Sb, rsb, s0, sg_swz, s_stride);
            pv64<<<dim3(pv_blocks, g), 256, 0, stream>>>(Hb, Sb, rsb,
                    content, mu, isd, out, s0, bg0, s_stride);
        }
    }
}

// Round 16
// 410.996 us; speedup vs baseline: 1.5010x; 1.0415x over previous
//
#include <hip/hip_runtime.h>
#include <hip/hip_bf16.h>
#include <math.h>

#define B_SZ 4
#define CDIM 512
#define NPIX 4096
#define EPSN 1e-5f

typedef unsigned short u16;
typedef __attribute__((ext_vector_type(8))) short bf16x8;
typedef __attribute__((ext_vector_type(4))) float f32x4;
typedef __attribute__((ext_vector_type(16))) float f32x16;

#define MFMA_BF16 __builtin_amdgcn_mfma_f32_16x16x32_bf16
#define MFMA32    __builtin_amdgcn_mfma_f32_32x32x16_bf16

// async global->LDS DMA, 16B per lane; LDS dest = wave-uniform base + lane*16
#define GLD16(gp, lp) __builtin_amdgcn_global_load_lds( \
    (const __attribute__((address_space(1))) void*)(gp), \
    (__attribute__((address_space(3))) void*)(lp), 16, 0, 0)

static __device__ __forceinline__ float bf2f(u16 u) {
    return __uint_as_float(((unsigned)u) << 16);
}
static __device__ __forceinline__ u16 f2bf(float f) {
    unsigned u = __float_as_uint(f);
    unsigned r = (u + 0x7FFFu + ((u >> 16) & 1u)) >> 16;
    return (u16)r;
}
// packed square of a bf16x8 fragment, truncating round; v_perm repack
static __device__ __forceinline__ bf16x8 sq_bf16x8(bf16x8 a) {
    union { bf16x8 v; unsigned w[4]; } in, out;
    in.v = a;
    #pragma unroll
    for (int k = 0; k < 4; k++) {
        unsigned wl = in.w[k] << 16;
        unsigned wh = in.w[k] & 0xFFFF0000u;
        float sl = __uint_as_float(wl); sl *= sl;
        float sh = __uint_as_float(wh); sh *= sh;
        out.w[k] = __builtin_amdgcn_perm(__float_as_uint(sh), __float_as_uint(sl),
                                         0x07060302u);
    }
    return out.v;
}

// ---------------------------------------------------------------------------
// transpose3b: z = gb*3 + which; source fp32 [CDIM][NPIX] (global batch
// bg0+gb) -> XT slab entry z, bf16 [NPIX][CDIM].
// ---------------------------------------------------------------------------
__global__ __launch_bounds__(256) void transpose3b(const float* __restrict__ X0,
    const float* __restrict__ X1, const float* __restrict__ X2,
    u16* __restrict__ XTbase, int bg0)
{
    const int z = blockIdx.z;
    const int gb = z / 3, which = z % 3;
    const size_t TBe = (size_t)CDIM * NPIX;
    const float* X = (which == 0 ? X0 : which == 1 ? X1 : X2) + (size_t)(bg0 + gb) * TBe;
    u16* XT = XTbase + (size_t)z * TBe;

    __shared__ float T[64][65];
    const int t = threadIdx.x;
    const int n0 = blockIdx.x * 64, c0 = blockIdx.y * 64;
    #pragma unroll
    for (int p = 0; p < 4; p++) {
        int c_l = (t >> 4) + p * 16;
        int n_l = (t & 15) * 4;
        float4 v = *(const float4*)&X[(size_t)(c0 + c_l) * NPIX + n0 + n_l];
        T[c_l][n_l+0] = v.x; T[c_l][n_l+1] = v.y; T[c_l][n_l+2] = v.z; T[c_l][n_l+3] = v.w;
    }
    __syncthreads();
    #pragma unroll
    for (int p = 0; p < 4; p++) {
        int n_l = t >> 2;
        int cs  = (t & 3) * 4 + p * 16;
        ushort4 r;
        r.x = f2bf(T[cs+0][n_l]); r.y = f2bf(T[cs+1][n_l]);
        r.z = f2bf(T[cs+2][n_l]); r.w = f2bf(T[cs+3][n_l]);
        *(ushort4*)&XT[(size_t)(n0 + n_l) * CDIM + c0 + cs] = r;
    }
}

// ---------------------------------------------------------------------------
// conv3b: z = gb*3 + which. D[o][n] = bias[o] + sum_c W[o][c]*XT[n][c].
// which<2: store D^T to (FT|GT)+gb*TB ([n][CDIM]); which==2: Hb+gb*TB.
// ---------------------------------------------------------------------------
__global__ __launch_bounds__(256) void conv3b(const u16* __restrict__ XTbase,
    const float* __restrict__ W0, const float* __restrict__ W1, const float* __restrict__ W2,
    const float* __restrict__ b0, const float* __restrict__ b1, const float* __restrict__ b2,
    u16* __restrict__ FTb, u16* __restrict__ GTb, u16* __restrict__ Hbb)
{
    const int z = blockIdx.z;
    const int gb = z / 3, which = z % 3;
    const size_t TBe = (size_t)CDIM * NPIX;
    const u16* XT = XTbase + (size_t)z * TBe;
    const float* W = which == 0 ? W0 : which == 1 ? W1 : W2;
    const float* bias = which == 0 ? b0 : which == 1 ? b1 : b2;

    const int t = threadIdx.x;
    const int lane = t & 63, wv = t >> 6;
    const int wr = wv >> 1, wc = wv & 1;
    const int n0 = blockIdx.x * 64;
    const int o0 = blockIdx.y * 64;
    const int g = lane >> 4, li = lane & 15;

    __shared__ short Aw[64][40];
    __shared__ short Bx[64][40];

    f32x4 acc[2][2] = {};
    const int srow = t >> 2, sseg = (t & 3) * 8;

    float4 w0 = *(const float4*)&W[(size_t)(o0 + srow) * CDIM + sseg];
    float4 w1 = *(const float4*)&W[(size_t)(o0 + srow) * CDIM + sseg + 4];
    bf16x8 bv = *(const bf16x8*)&XT[(size_t)(n0 + srow) * CDIM + sseg];

    for (int kb = 0; kb < CDIM; kb += 32) {
        bf16x8 wa;
        wa[0] = (short)f2bf(w0.x); wa[1] = (short)f2bf(w0.y);
        wa[2] = (short)f2bf(w0.z); wa[3] = (short)f2bf(w0.w);
        wa[4] = (short)f2bf(w1.x); wa[5] = (short)f2bf(w1.y);
        wa[6] = (short)f2bf(w1.z); wa[7] = (short)f2bf(w1.w);
        __syncthreads();
        *(bf16x8*)&Aw[srow][sseg] = wa;
        *(bf16x8*)&Bx[srow][sseg] = bv;
        if (kb + 32 < CDIM) {
            w0 = *(const float4*)&W[(size_t)(o0 + srow) * CDIM + kb + 32 + sseg];
            w1 = *(const float4*)&W[(size_t)(o0 + srow) * CDIM + kb + 32 + sseg + 4];
            bv = *(const bf16x8*)&XT[(size_t)(n0 + srow) * CDIM + kb + 32 + sseg];
        }
        __syncthreads();
        bf16x8 a[2], b[2];
        #pragma unroll
        for (int i = 0; i < 2; i++) a[i] = *(const bf16x8*)&Aw[wr*32 + i*16 + li][g*8];
        #pragma unroll
        for (int j = 0; j < 2; j++) b[j] = *(const bf16x8*)&Bx[wc*32 + j*16 + li][g*8];
        #pragma unroll
        for (int i = 0; i < 2; i++)
            #pragma unroll
            for (int j = 0; j < 2; j++)
                acc[i][j] = MFMA_BF16(a[i], b[j], acc[i][j], 0, 0, 0);
    }

    #pragma unroll
    for (int i = 0; i < 2; i++) {
        const int orow = o0 + wr*32 + i*16 + 4*g;
        float4 bs = *(const float4*)&bias[orow];
        #pragma unroll
        for (int j = 0; j < 2; j++) {
            const int ncol = n0 + wc*32 + j*16 + li;
            if (which < 2) {
                u16* Y = (which == 0 ? FTb : GTb) + (size_t)gb * TBe;
                ushort4 r;
                r.x = f2bf(acc[i][j][0] + bs.x);
                r.y = f2bf(acc[i][j][1] + bs.y);
                r.z = f2bf(acc[i][j][2] + bs.z);
                r.w = f2bf(acc[i][j][3] + bs.w);
                *(ushort4*)&Y[(size_t)ncol * CDIM + orow] = r;
            } else {
                u16* Y2 = Hbb + (size_t)gb * TBe;
                const float bb[4] = { bs.x, bs.y, bs.z, bs.w };
                #pragma unroll
                for (int r = 0; r < 4; r++)
                    Y2[(size_t)(orow + r) * NPIX + ncol] = f2bf(acc[i][j][r] + bb[r]);
            }
        }
    }
}

// ---------------------------------------------------------------------------
// norm2b: blockIdx.y = gb*2 + z. z=0: Fn[gb][n], rs[gb][n]=0 ; z=1: Gn[gb][n]
// ---------------------------------------------------------------------------
__global__ __launch_bounds__(256) void norm2b(const u16* __restrict__ FT,
    const u16* __restrict__ GT, float* __restrict__ Fn, float* __restrict__ Gn,
    float* __restrict__ rs)
{
    const int gb = blockIdx.y >> 1, z = blockIdx.y & 1;
    const size_t TBe = (size_t)CDIM * NPIX;
    const int n = blockIdx.x * 256 + threadIdx.x;
    const u16* row = ((z ? GT : FT) + (size_t)gb * TBe) + (size_t)n * CDIM;
    float s = 0.f;
    for (int c = 0; c < CDIM; c += 8) {
        bf16x8 v = *(const bf16x8*)&row[c];
        #pragma unroll
        for (int e = 0; e < 8; e++) { float f = bf2f((u16)v[e]); s += f * f; }
    }
    ((z ? Gn : Fn) + (size_t)gb * NPIX)[n] = sqrtf(s);
    if (!z) rs[(size_t)gb * NPIX + n] = 0.f;
}

// ---------------------------------------------------------------------------
// s_gemm128: S[nl][m] = bf16(relu(dot/((Fn+e)(Gn+e)) + 1)), + rowsum atomics.
// 128x128 tile, 4 waves (2x2 of 64x64), K-step 32, gld_lds DMA staging with
// source-side swizzle. blockIdx.y = group-local batch gb. (unchanged r15)
// ---------------------------------------------------------------------------
__global__ __launch_bounds__(256) void s_gemm128(const u16* __restrict__ FTb,
    const u16* __restrict__ GTb, const float* __restrict__ Fnb, const float* __restrict__ Gnb,
    u16* __restrict__ Sbase, float* __restrict__ rsb, int strip_base, int swz,
    size_t s_stride)
{
    const int gb = blockIdx.y;
    const size_t TBe = (size_t)CDIM * NPIX;
    const u16* FT = FTb + (size_t)gb * TBe;
    const u16* GT = GTb + (size_t)gb * TBe;
    const float* Fn = Fnb + (size_t)gb * NPIX;
    const float* Gn = Gnb + (size_t)gb * NPIX;
    u16* S = Sbase + (size_t)gb * s_stride;
    float* rs = rsb + (size_t)gb * NPIX;

    const int t = threadIdx.x;
    const int lane = t & 63, wv = t >> 6;
    const int wr = wv >> 1, wc = wv & 1;

    int mm, nn;
    if (swz) {            // (ns/128) % 8 == 0
        const int xk = blockIdx.x & 7, q = blockIdx.x >> 3;
        mm = q & 31;                      // NPIX/128 == 32
        nn = (q >> 5) * 8 + xk;
    } else {
        mm = blockIdx.x & 31;
        nn = blockIdx.x >> 5;
    }
    const int m0  = mm * 128;
    const int nl0 = nn * 128;
    const int ng0 = strip_base + nl0;
    const int g = lane >> 4, li = lane & 15;

    __shared__ short Cs[2][128][64];   // 32 KB total

    f32x4 acc[4][4] = {};

    const int lr = lane >> 3, lq = lane & 7;

    #define SG_STAGE(BUF, KB)                                                  \
    {                                                                          \
        _Pragma("unroll")                                                      \
        for (int ch = 0; ch < 4; ch++) {                                       \
            const int r0 = wv*32 + ch*8;                                       \
            const int r  = r0 + lr;                                            \
            const int c  = lq ^ (r & 7);                                       \
            const u16* gp = (c < 4)                                            \
                ? &FT[(size_t)(ng0 + r) * CDIM + (KB) + c*8]                   \
                : &GT[(size_t)(m0  + r) * CDIM + (KB) + (c-4)*8];              \
            GLD16(gp, &Cs[BUF][r0][0]);                                        \
        }                                                                      \
    }

    SG_STAGE(0, 0);
    __syncthreads();

    int buf = 0;
    for (int kb = 0; kb < CDIM; kb += 32) {
        if (kb + 32 < CDIM) SG_STAGE(buf ^ 1, kb + 32);
        bf16x8 a[4], b[4];
        #pragma unroll
        for (int i = 0; i < 4; i++) {
            const int row = wr*64 + i*16 + li;
            a[i] = *(const bf16x8*)&Cs[buf][row][(g ^ (row & 7)) * 8];
        }
        #pragma unroll
        for (int j = 0; j < 4; j++) {
            const int row = wc*64 + j*16 + li;
            b[j] = *(const bf16x8*)&Cs[buf][row][((4 + g) ^ (row & 7)) * 8];
        }
        #pragma unroll
        for (int i = 0; i < 4; i++)
            #pragma unroll
            for (int j = 0; j < 4; j++)
                acc[i][j] = MFMA_BF16(a[i], b[j], acc[i][j], 0, 0, 0);
        __syncthreads();
        buf ^= 1;
    }
    #undef SG_STAGE

    float gi[4];
    #pragma unroll
    for (int j = 0; j < 4; j++) gi[j] = 1.f / (Gn[m0 + wc*64 + j*16 + li] + EPSN);
    #pragma unroll
    for (int i = 0; i < 4; i++) {
        const int nl = nl0 + wr*64 + i*16 + 4*g;
        float4 fn4 = *(const float4*)&Fn[strip_base + nl];
        const float fi4[4] = { 1.f/(fn4.x + EPSN), 1.f/(fn4.y + EPSN),
                               1.f/(fn4.z + EPSN), 1.f/(fn4.w + EPSN) };
        float ps[4] = {0.f, 0.f, 0.f, 0.f};
        #pragma unroll
        for (int j = 0; j < 4; j++) {
            const int m = m0 + wc*64 + j*16 + li;
            #pragma unroll
            for (int r = 0; r < 4; r++) {
                float v = fmaxf(acc[i][j][r] * fi4[r] * gi[j] + 1.f, 0.f);
                u16 hv = f2bf(v);
                S[(size_t)(nl + r) * NPIX + m] = hv;
                ps[r] += bf2f(hv);
            }
        }
        #pragma unroll
        for (int r = 0; r < 4; r++) {
            float p = ps[r];
            p += __shfl_xor(p, 1);
            p += __shfl_xor(p, 2);
            p += __shfl_xor(p, 4);
            p += __shfl_xor(p, 8);
            if (li == 0) atomicAdd(&rs[strip_base + nl + r], p);
        }
    }
}

// ---------------------------------------------------------------------------
// pv64x128: mean/msq via MFMA 32x32x16 (dual chains, H^2 in-register).
// Tile 64c x 128n, 256 threads / 4 waves (2wr x 2wc), wave-tile 32c x 64n:
// per phase 16 MFMA vs 4 sq-calls (VALU/MFMA halved vs 64x64) and logical
// L2/L3 traffic -25% (r15 profile: VALU 69%, ~10.4 TB/s cache traffic).
// LDS: r13-proven 16-slot XOR involution, extended to 96 rows:
//   rows 0-63:  slots(log) 0-7 = H row r, 8-15 = S row r
//   rows 64-95: slots(log) 0-7 = S row r, 8-15 = S row r+32
// phys slot = logical ^ (row&15), applied on DMA-source AND read (rule 21).
// 48 KB LDS -> 3 blocks/CU; grid 256/batch x nb keeps block-TLP (r14 lesson:
// 256-thread blocks, not 512). launch_bounds(256,3): 64 acc VGPRs need the
// budget (r12 lesson: default 64-cap would wreck this kernel).
// ---------------------------------------------------------------------------
__global__ __launch_bounds__(256, 3) void pv64x128(const u16* __restrict__ Hbb,
    const u16* __restrict__ Sbase, const float* __restrict__ rsb,
    const float* __restrict__ content, const float* __restrict__ mub,
    const float* __restrict__ isdb, float* __restrict__ out, int strip_base,
    int bg0, size_t s_stride, int swz)
{
    const int gb = blockIdx.y;
    const size_t TBe = (size_t)CDIM * NPIX;
    const u16* Hb = Hbb + (size_t)gb * TBe;
    const u16* Sb = Sbase + (size_t)gb * s_stride;
    const float* rs = rsb + (size_t)gb * NPIX;
    const float* content_b = content + (size_t)(bg0 + gb) * TBe;
    const float* mu  = mub  + (size_t)(bg0 + gb) * CDIM;
    const float* isd = isdb + (size_t)(bg0 + gb) * CDIM;
    float* out_b = out + (size_t)(bg0 + gb) * TBe;

    const int t = threadIdx.x;
    const int lane = t & 63, wv = t >> 6;
    const int wr = wv >> 1, wc = wv & 1;
    const int l31 = lane & 31, h = lane >> 5;

    int c_t, n_t;
    if (swz) {          // (ns/128) % 8 == 0
        const int xk = blockIdx.x & 7, q = blockIdx.x >> 3;
        c_t = q & 7;                            // CDIM/64 == 8
        n_t = (q >> 3) * 8 + xk;
    } else {
        c_t = blockIdx.x & 7;
        n_t = blockIdx.x >> 3;
    }
    const int c0  = c_t * 64;
    const int nl0 = n_t * 128;

    __shared__ short AS[2][96][128];            // 2 x 24 KB

    f32x16 am0 = {}, am1 = {}, aq0 = {}, aq1 = {};

    const int lr = lane >> 4, lq = lane & 15;

    #define PV_STAGE(BUF, KB)                                                  \
    {                                                                          \
        _Pragma("unroll")                                                      \
        for (int ch = 0; ch < 6; ch++) {                                       \
            const int r0 = wv*24 + ch*4;                                       \
            const int r  = r0 + lr;                                            \
            const int c  = lq ^ (r & 15);                                      \
            const u16* gp;                                                     \
            if (r0 < 64)                                                       \
                gp = (c < 8)                                                   \
                    ? &Hb[(size_t)(c0  + r) * NPIX + (KB) + c*8]               \
                    : &Sb[(size_t)(nl0 + r) * NPIX + (KB) + (c-8)*8];          \
            else                                                               \
                gp = (c < 8)                                                   \
                    ? &Sb[(size_t)(nl0 + r     ) * NPIX + (KB) + c*8]          \
                    : &Sb[(size_t)(nl0 + r + 32) * NPIX + (KB) + (c-8)*8];     \
            GLD16(gp, &AS[BUF][r0][0]);                                        \
        }                                                                      \
    }

    const int prow_a  = wr*32 + l31;                    // H row 0..63
    const int prow_b0 = wc ? (64 + l31) : l31;          // S row j=0
    const int sb_b0   = wc ? 0 : 8;
    const int prow_b1 = wc ? (64 + l31) : (32 + l31);   // S row j=1
    const int swa  = prow_a  & 15;
    const int swb0 = prow_b0 & 15;
    const int swb1 = prow_b1 & 15;

    PV_STAGE(0, 0);
    __syncthreads();

    int buf = 0;
    for (int kb = 0; kb < NPIX; kb += 64) {
        if (kb + 64 < NPIX) PV_STAGE(buf ^ 1, kb + 64);
        const short* rpa  = &AS[buf][prow_a ][0];
        const short* rpb0 = &AS[buf][prow_b0][0];
        const short* rpb1 = &AS[buf][prow_b1][0];
        #pragma unroll
        for (int ks = 0; ks < 4; ks++) {
            const int sg = ks*2 + h;
            bf16x8 a  = *(const bf16x8*)&rpa [((sg        ) ^ swa ) * 8];
            bf16x8 b0 = *(const bf16x8*)&rpb0[((sb_b0 + sg) ^ swb0) * 8];
            bf16x8 b1 = *(const bf16x8*)&rpb1[((8     + sg) ^ swb1) * 8];
            bf16x8 a2 = sq_bf16x8(a);
            am0 = MFMA32(a,  b0, am0, 0, 0, 0);
            am1 = MFMA32(a,  b1, am1, 0, 0, 0);
            aq0 = MFMA32(a2, b0, aq0, 0, 0, 0);
            aq1 = MFMA32(a2, b1, aq1, 0, 0, 0);
        }
        __syncthreads();
        buf ^= 1;
    }
    #undef PV_STAGE

    // C layout (32x32): col = lane&31 (n), row = (reg&3) + 8*(reg>>2) + 4*h (c)
    #pragma unroll
    for (int j = 0; j < 2; j++) {
        const int n = strip_base + nl0 + wc*64 + j*32 + l31;
        const float inv = 1.f / (rs[n] + EPSN);
        const f32x16& am = j ? am1 : am0;
        const f32x16& aq = j ? aq1 : aq0;
        #pragma unroll
        for (int qd = 0; qd < 4; qd++) {
            const int cb = c0 + wr*32 + 8*qd + 4*h;
            float4 mu4 = *(const float4*)&mu[cb];
            float4 is4 = *(const float4*)&isd[cb];
            const float muA[4] = { mu4.x, mu4.y, mu4.z, mu4.w };
            const float isA[4] = { is4.x, is4.y, is4.z, is4.w };
            #pragma unroll
            for (int r2 = 0; r2 < 4; r2++) {
                const int reg = qd*4 + r2;
                float mean = am[reg] * inv;
                float msq  = aq[reg] * inv;
                float sd   = sqrtf(fmaxf(msq - mean*mean, 0.f));
                float cv   = content_b[(size_t)(cb + r2) * NPIX + n];
                out_b[(size_t)(cb + r2) * NPIX + n] = sd * (cv - muA[r2]) * isA[r2] + mean;
            }
        }
    }
}

// ---------------------------------------------------------------------------
// content_stats: per (b,c) mean and 1/std (unbiased var, +1e-5), fp32 input
// ---------------------------------------------------------------------------
__global__ __launch_bounds__(256) void content_stats(const float* __restrict__ x,
    float* __restrict__ mu, float* __restrict__ isd)
{
    const int bc = blockIdx.x;
    const int tid = threadIdx.x;
    const float* row = x + (size_t)bc * NPIX;
    float s = 0.f, s2 = 0.f;
    for (int i = tid * 4; i < NPIX; i += 256 * 4) {
        float4 v = *(const float4*)&row[i];
        s  += v.x + v.y + v.z + v.w;
        s2 += v.x*v.x + v.y*v.y + v.z*v.z + v.w*v.w;
    }
    __shared__ float r1[256], r2[256];
    r1[tid] = s; r2[tid] = s2; __syncthreads();
    for (int st = 128; st; st >>= 1) {
        if (tid < st) { r1[tid] += r1[tid+st]; r2[tid] += r2[tid+st]; }
        __syncthreads();
    }
    if (tid == 0) {
        float m = r1[0] / NPIX;
        float var = (r2[0] - (float)NPIX * m * m) / (float)(NPIX - 1);
        mu[bc]  = m;
        isd[bc] = rsqrtf(var + 1e-5f);
    }
}

// ---------------------------------------------------------------------------
extern "C" void kernel_launch(void* const* d_in, const int* in_sizes, int n_in,
                              void* d_out, int out_size, void* d_ws, size_t ws_size,
                              hipStream_t stream)
{
    const float* content     = (const float*)d_in[0];
    const float* style       = (const float*)d_in[1];
    const float* content_key = (const float*)d_in[2];
    const float* style_key   = (const float*)d_in[3];
    const float* Wf  = (const float*)d_in[4];
    const float* bf_ = (const float*)d_in[5];
    const float* Wg  = (const float*)d_in[6];
    const float* bg  = (const float*)d_in[7];
    const float* Wh  = (const float*)d_in[8];
    const float* bh  = (const float*)d_in[9];
    float* out = (float*)d_out;

    const size_t TB = (size_t)CDIM * NPIX;   // elems per batch-tensor
    const size_t tail_bytes = (3 * (size_t)B_SZ * NPIX + 2 * (size_t)B_SZ * CDIM) * 4 + 256;

    // choose (nb, ns): bytes = nb*(6*TB + NPIX*ns)*2 + tail
    int nb = 1, ns = 512;
    {
        const int nbc[5] = {4, 2, 4, 2, 1};
        const int nsc[5] = {4096, 4096, 2048, 2048, 4096};
        bool found = false;
        for (int i = 0; i < 5; i++) {
            size_t need = (size_t)nbc[i] * (6 * TB + (size_t)NPIX * nsc[i]) * 2 + tail_bytes;
            if (need <= ws_size) { nb = nbc[i]; ns = nsc[i]; found = true; break; }
        }
        if (!found) {
            nb = 1;
            for (int cand = 2048; cand >= 512; cand >>= 1) {
                size_t need = (6 * TB + (size_t)NPIX * cand) * 2 + tail_bytes;
                if (need <= ws_size) { ns = cand; break; }
            }
        }
    }
    const size_t s_stride = (size_t)NPIX * ns;   // elems per batch S strip

    u16* FT  = (u16*)d_ws;                   // nb x [NPIX][CDIM]
    u16* GT  = FT + (size_t)nb * TB;
    u16* Hb  = GT + (size_t)nb * TB;         // nb x [CDIM][NPIX]
    u16* XT  = Hb + (size_t)nb * TB;         // nb*3 x [NPIX][CDIM]
    u16* Sb  = XT + (size_t)nb * 3 * TB;     // nb x [ns][NPIX]
    float* Fn  = (float*)(Sb + (size_t)nb * s_stride);
    float* Gn  = Fn + (size_t)B_SZ * NPIX;
    float* rsb = Gn + (size_t)B_SZ * NPIX;
    float* mu  = rsb + (size_t)B_SZ * NPIX;
    float* isd = mu + (size_t)B_SZ * CDIM;

    content_stats<<<B_SZ * CDIM, 256, 0, stream>>>(content, mu, isd);

    const int sg_swz = ((ns / 128) % 8 == 0) ? 1 : 0;
    const int sg_blocks = (NPIX / 128) * (ns / 128);
    const int pv_swz = ((ns / 128) % 8 == 0) ? 1 : 0;
    const int pv_blocks = 8 * (ns / 128);

    for (int bg0 = 0; bg0 < B_SZ; bg0 += nb) {
        const int g = (bg0 + nb <= B_SZ) ? nb : (B_SZ - bg0);

        transpose3b<<<dim3(NPIX/64, CDIM/64, 3*g), 256, 0, stream>>>(
                content_key, style_key, style, XT, bg0);

        conv3b<<<dim3(NPIX/64, CDIM/64, 3*g), 256, 0, stream>>>(
                XT, Wf, Wg, Wh, bf_, bg, bh, FT, GT, Hb);

        norm2b<<<dim3(NPIX/256, 2*g), 256, 0, stream>>>(FT, GT, Fn, Gn, rsb);

        for (int s0 = 0; s0 < NPIX; s0 += ns) {
            s_gemm128<<<dim3(sg_blocks, g), 256, 0, stream>>>(FT, GT, Fn, Gn,
                    Sb, rsb, s0, sg_swz, s_stride);
            pv64x128<<<dim3(pv_blocks, g), 256, 0, stream>>>(Hb, Sb, rsb,
                    content, mu, isd, out, s0, bg0, s_stride, pv_swz);
        }
    }
}

// Round 17
// 387.516 us; speedup vs baseline: 1.5919x; 1.0606x over previous
//
#include <hip/hip_runtime.h>
#include <hip/hip_bf16.h>
#include <math.h>

#define B_SZ 4
#define CDIM 512
#define NPIX 4096
#define EPSN 1e-5f

typedef unsigned short u16;
typedef __attribute__((ext_vector_type(8))) short bf16x8;
typedef __attribute__((ext_vector_type(4))) float f32x4;
typedef __attribute__((ext_vector_type(16))) float f32x16;

#define MFMA_BF16 __builtin_amdgcn_mfma_f32_16x16x32_bf16
#define MFMA32    __builtin_amdgcn_mfma_f32_32x32x16_bf16

// async global->LDS DMA, 16B per lane; LDS dest = wave-uniform base + lane*16
#define GLD16(gp, lp) __builtin_amdgcn_global_load_lds( \
    (const __attribute__((address_space(1))) void*)(gp), \
    (__attribute__((address_space(3))) void*)(lp), 16, 0, 0)

static __device__ __forceinline__ float bf2f(u16 u) {
    return __uint_as_float(((unsigned)u) << 16);
}
static __device__ __forceinline__ u16 f2bf(float f) {
    unsigned u = __float_as_uint(f);
    unsigned r = (u + 0x7FFFu + ((u >> 16) & 1u)) >> 16;
    return (u16)r;
}
// packed square of a bf16x8 fragment, truncating round; v_perm repack
static __device__ __forceinline__ bf16x8 sq_bf16x8(bf16x8 a) {
    union { bf16x8 v; unsigned w[4]; } in, out;
    in.v = a;
    #pragma unroll
    for (int k = 0; k < 4; k++) {
        unsigned wl = in.w[k] << 16;
        unsigned wh = in.w[k] & 0xFFFF0000u;
        float sl = __uint_as_float(wl); sl *= sl;
        float sh = __uint_as_float(wh); sh *= sh;
        out.w[k] = __builtin_amdgcn_perm(__float_as_uint(sh), __float_as_uint(sl),
                                         0x07060302u);
    }
    return out.v;
}

// ---------------------------------------------------------------------------
// transpose3b: z = gb*3 + which; source fp32 [CDIM][NPIX] (global batch
// bg0+gb) -> XT slab entry z, bf16 [NPIX][CDIM].
// ---------------------------------------------------------------------------
__global__ __launch_bounds__(256) void transpose3b(const float* __restrict__ X0,
    const float* __restrict__ X1, const float* __restrict__ X2,
    u16* __restrict__ XTbase, int bg0)
{
    const int z = blockIdx.z;
    const int gb = z / 3, which = z % 3;
    const size_t TBe = (size_t)CDIM * NPIX;
    const float* X = (which == 0 ? X0 : which == 1 ? X1 : X2) + (size_t)(bg0 + gb) * TBe;
    u16* XT = XTbase + (size_t)z * TBe;

    __shared__ float T[64][65];
    const int t = threadIdx.x;
    const int n0 = blockIdx.x * 64, c0 = blockIdx.y * 64;
    #pragma unroll
    for (int p = 0; p < 4; p++) {
        int c_l = (t >> 4) + p * 16;
        int n_l = (t & 15) * 4;
        float4 v = *(const float4*)&X[(size_t)(c0 + c_l) * NPIX + n0 + n_l];
        T[c_l][n_l+0] = v.x; T[c_l][n_l+1] = v.y; T[c_l][n_l+2] = v.z; T[c_l][n_l+3] = v.w;
    }
    __syncthreads();
    #pragma unroll
    for (int p = 0; p < 4; p++) {
        int n_l = t >> 2;
        int cs  = (t & 3) * 4 + p * 16;
        ushort4 r;
        r.x = f2bf(T[cs+0][n_l]); r.y = f2bf(T[cs+1][n_l]);
        r.z = f2bf(T[cs+2][n_l]); r.w = f2bf(T[cs+3][n_l]);
        *(ushort4*)&XT[(size_t)(n0 + n_l) * CDIM + c0 + cs] = r;
    }
}

// ---------------------------------------------------------------------------
// conv3b: z = gb*3 + which. D[o][n] = bias[o] + sum_c W[o][c]*XT[n][c].
// which<2: store D^T to (FT|GT)+gb*TB ([n][CDIM]); which==2: Hb+gb*TB.
// ---------------------------------------------------------------------------
__global__ __launch_bounds__(256) void conv3b(const u16* __restrict__ XTbase,
    const float* __restrict__ W0, const float* __restrict__ W1, const float* __restrict__ W2,
    const float* __restrict__ b0, const float* __restrict__ b1, const float* __restrict__ b2,
    u16* __restrict__ FTb, u16* __restrict__ GTb, u16* __restrict__ Hbb)
{
    const int z = blockIdx.z;
    const int gb = z / 3, which = z % 3;
    const size_t TBe = (size_t)CDIM * NPIX;
    const u16* XT = XTbase + (size_t)z * TBe;
    const float* W = which == 0 ? W0 : which == 1 ? W1 : W2;
    const float* bias = which == 0 ? b0 : which == 1 ? b1 : b2;

    const int t = threadIdx.x;
    const int lane = t & 63, wv = t >> 6;
    const int wr = wv >> 1, wc = wv & 1;
    const int n0 = blockIdx.x * 64;
    const int o0 = blockIdx.y * 64;
    const int g = lane >> 4, li = lane & 15;

    __shared__ short Aw[64][40];
    __shared__ short Bx[64][40];

    f32x4 acc[2][2] = {};
    const int srow = t >> 2, sseg = (t & 3) * 8;

    float4 w0 = *(const float4*)&W[(size_t)(o0 + srow) * CDIM + sseg];
    float4 w1 = *(const float4*)&W[(size_t)(o0 + srow) * CDIM + sseg + 4];
    bf16x8 bv = *(const bf16x8*)&XT[(size_t)(n0 + srow) * CDIM + sseg];

    for (int kb = 0; kb < CDIM; kb += 32) {
        bf16x8 wa;
        wa[0] = (short)f2bf(w0.x); wa[1] = (short)f2bf(w0.y);
        wa[2] = (short)f2bf(w0.z); wa[3] = (short)f2bf(w0.w);
        wa[4] = (short)f2bf(w1.x); wa[5] = (short)f2bf(w1.y);
        wa[6] = (short)f2bf(w1.z); wa[7] = (short)f2bf(w1.w);
        __syncthreads();
        *(bf16x8*)&Aw[srow][sseg] = wa;
        *(bf16x8*)&Bx[srow][sseg] = bv;
        if (kb + 32 < CDIM) {
            w0 = *(const float4*)&W[(size_t)(o0 + srow) * CDIM + kb + 32 + sseg];
            w1 = *(const float4*)&W[(size_t)(o0 + srow) * CDIM + kb + 32 + sseg + 4];
            bv = *(const bf16x8*)&XT[(size_t)(n0 + srow) * CDIM + kb + 32 + sseg];
        }
        __syncthreads();
        bf16x8 a[2], b[2];
        #pragma unroll
        for (int i = 0; i < 2; i++) a[i] = *(const bf16x8*)&Aw[wr*32 + i*16 + li][g*8];
        #pragma unroll
        for (int j = 0; j < 2; j++) b[j] = *(const bf16x8*)&Bx[wc*32 + j*16 + li][g*8];
        #pragma unroll
        for (int i = 0; i < 2; i++)
            #pragma unroll
            for (int j = 0; j < 2; j++)
                acc[i][j] = MFMA_BF16(a[i], b[j], acc[i][j], 0, 0, 0);
    }

    #pragma unroll
    for (int i = 0; i < 2; i++) {
        const int orow = o0 + wr*32 + i*16 + 4*g;
        float4 bs = *(const float4*)&bias[orow];
        #pragma unroll
        for (int j = 0; j < 2; j++) {
            const int ncol = n0 + wc*32 + j*16 + li;
            if (which < 2) {
                u16* Y = (which == 0 ? FTb : GTb) + (size_t)gb * TBe;
                ushort4 r;
                r.x = f2bf(acc[i][j][0] + bs.x);
                r.y = f2bf(acc[i][j][1] + bs.y);
                r.z = f2bf(acc[i][j][2] + bs.z);
                r.w = f2bf(acc[i][j][3] + bs.w);
                *(ushort4*)&Y[(size_t)ncol * CDIM + orow] = r;
            } else {
                u16* Y2 = Hbb + (size_t)gb * TBe;
                const float bb[4] = { bs.x, bs.y, bs.z, bs.w };
                #pragma unroll
                for (int r = 0; r < 4; r++)
                    Y2[(size_t)(orow + r) * NPIX + ncol] = f2bf(acc[i][j][r] + bb[r]);
            }
        }
    }
}

// ---------------------------------------------------------------------------
// norm2b: blockIdx.y = gb*2 + z. z=0: Fn[gb][n], rs[gb][n]=0 ; z=1: Gn[gb][n]
// ---------------------------------------------------------------------------
__global__ __launch_bounds__(256) void norm2b(const u16* __restrict__ FT,
    const u16* __restrict__ GT, float* __restrict__ Fn, float* __restrict__ Gn,
    float* __restrict__ rs)
{
    const int gb = blockIdx.y >> 1, z = blockIdx.y & 1;
    const size_t TBe = (size_t)CDIM * NPIX;
    const int n = blockIdx.x * 256 + threadIdx.x;
    const u16* row = ((z ? GT : FT) + (size_t)gb * TBe) + (size_t)n * CDIM;
    float s = 0.f;
    for (int c = 0; c < CDIM; c += 8) {
        bf16x8 v = *(const bf16x8*)&row[c];
        #pragma unroll
        for (int e = 0; e < 8; e++) { float f = bf2f((u16)v[e]); s += f * f; }
    }
    ((z ? Gn : Fn) + (size_t)gb * NPIX)[n] = sqrtf(s);
    if (!z) rs[(size_t)gb * NPIX + n] = 0.f;
}

// ---------------------------------------------------------------------------
// s_gemm128: S[nl][m] = bf16(relu(dot/((Fn+e)(Gn+e)) + 1)), + rowsum atomics.
// 128x128 tile, 4 waves (2x2 of 64x64), K-step 32, gld_lds DMA staging with
// source-side swizzle. blockIdx.y = group-local batch gb. (unchanged)
// ---------------------------------------------------------------------------
__global__ __launch_bounds__(256) void s_gemm128(const u16* __restrict__ FTb,
    const u16* __restrict__ GTb, const float* __restrict__ Fnb, const float* __restrict__ Gnb,
    u16* __restrict__ Sbase, float* __restrict__ rsb, int strip_base, int swz,
    size_t s_stride)
{
    const int gb = blockIdx.y;
    const size_t TBe = (size_t)CDIM * NPIX;
    const u16* FT = FTb + (size_t)gb * TBe;
    const u16* GT = GTb + (size_t)gb * TBe;
    const float* Fn = Fnb + (size_t)gb * NPIX;
    const float* Gn = Gnb + (size_t)gb * NPIX;
    u16* S = Sbase + (size_t)gb * s_stride;
    float* rs = rsb + (size_t)gb * NPIX;

    const int t = threadIdx.x;
    const int lane = t & 63, wv = t >> 6;
    const int wr = wv >> 1, wc = wv & 1;

    int mm, nn;
    if (swz) {            // (ns/128) % 8 == 0
        const int xk = blockIdx.x & 7, q = blockIdx.x >> 3;
        mm = q & 31;                      // NPIX/128 == 32
        nn = (q >> 5) * 8 + xk;
    } else {
        mm = blockIdx.x & 31;
        nn = blockIdx.x >> 5;
    }
    const int m0  = mm * 128;
    const int nl0 = nn * 128;
    const int ng0 = strip_base + nl0;
    const int g = lane >> 4, li = lane & 15;

    __shared__ short Cs[2][128][64];   // 32 KB total

    f32x4 acc[4][4] = {};

    const int lr = lane >> 3, lq = lane & 7;

    #define SG_STAGE(BUF, KB)                                                  \
    {                                                                          \
        _Pragma("unroll")                                                      \
        for (int ch = 0; ch < 4; ch++) {                                       \
            const int r0 = wv*32 + ch*8;                                       \
            const int r  = r0 + lr;                                            \
            const int c  = lq ^ (r & 7);                                       \
            const u16* gp = (c < 4)                                            \
                ? &FT[(size_t)(ng0 + r) * CDIM + (KB) + c*8]                   \
                : &GT[(size_t)(m0  + r) * CDIM + (KB) + (c-4)*8];              \
            GLD16(gp, &Cs[BUF][r0][0]);                                        \
        }                                                                      \
    }

    SG_STAGE(0, 0);
    __syncthreads();

    int buf = 0;
    for (int kb = 0; kb < CDIM; kb += 32) {
        if (kb + 32 < CDIM) SG_STAGE(buf ^ 1, kb + 32);
        bf16x8 a[4], b[4];
        #pragma unroll
        for (int i = 0; i < 4; i++) {
            const int row = wr*64 + i*16 + li;
            a[i] = *(const bf16x8*)&Cs[buf][row][(g ^ (row & 7)) * 8];
        }
        #pragma unroll
        for (int j = 0; j < 4; j++) {
            const int row = wc*64 + j*16 + li;
            b[j] = *(const bf16x8*)&Cs[buf][row][((4 + g) ^ (row & 7)) * 8];
        }
        #pragma unroll
        for (int i = 0; i < 4; i++)
            #pragma unroll
            for (int j = 0; j < 4; j++)
                acc[i][j] = MFMA_BF16(a[i], b[j], acc[i][j], 0, 0, 0);
        __syncthreads();
        buf ^= 1;
    }
    #undef SG_STAGE

    float gi[4];
    #pragma unroll
    for (int j = 0; j < 4; j++) gi[j] = 1.f / (Gn[m0 + wc*64 + j*16 + li] + EPSN);
    #pragma unroll
    for (int i = 0; i < 4; i++) {
        const int nl = nl0 + wr*64 + i*16 + 4*g;
        float4 fn4 = *(const float4*)&Fn[strip_base + nl];
        const float fi4[4] = { 1.f/(fn4.x + EPSN), 1.f/(fn4.y + EPSN),
                               1.f/(fn4.z + EPSN), 1.f/(fn4.w + EPSN) };
        float ps[4] = {0.f, 0.f, 0.f, 0.f};
        #pragma unroll
        for (int j = 0; j < 4; j++) {
            const int m = m0 + wc*64 + j*16 + li;
            #pragma unroll
            for (int r = 0; r < 4; r++) {
                float v = fmaxf(acc[i][j][r] * fi4[r] * gi[j] + 1.f, 0.f);
                u16 hv = f2bf(v);
                S[(size_t)(nl + r) * NPIX + m] = hv;
                ps[r] += bf2f(hv);
            }
        }
        #pragma unroll
        for (int r = 0; r < 4; r++) {
            float p = ps[r];
            p += __shfl_xor(p, 1);
            p += __shfl_xor(p, 2);
            p += __shfl_xor(p, 4);
            p += __shfl_xor(p, 8);
            if (li == 0) atomicAdd(&rs[strip_base + nl + r], p);
        }
    }
}

// ---------------------------------------------------------------------------
// pv128: mean/msq via MFMA 32x32x16 (dual chains, H^2 in-register).
// Tile 128c x 128n per block, 4 waves of 64c x 64n (2x2). Reads/MFMA = 0.5
// (was 0.75) — r16 arithmetic showed pv is LDS-read-throughput-bound
// (144 b128/CU-phase vs 384 cyc MFMA). Also -33% L2/L3 traffic.
// LDS: 2 x [128 rows x 256B]; row q = [H row q (slots 0-7) | S row q (8-15)],
// phys slot = logical ^ (q&15), involution on DMA-source AND read (rule 21).
// 64 KB LDS -> 2 blocks/CU; launch_bounds(256,2) for 128 acc VGPRs.
// ---------------------------------------------------------------------------
__global__ __launch_bounds__(256, 2) void pv128(const u16* __restrict__ Hbb,
    const u16* __restrict__ Sbase, const float* __restrict__ rsb,
    const float* __restrict__ content, const float* __restrict__ mub,
    const float* __restrict__ isdb, float* __restrict__ out, int strip_base,
    int bg0, size_t s_stride, int swz)
{
    const int gb = blockIdx.y;
    const size_t TBe = (size_t)CDIM * NPIX;
    const u16* Hb = Hbb + (size_t)gb * TBe;
    const u16* Sb = Sbase + (size_t)gb * s_stride;
    const float* rs = rsb + (size_t)gb * NPIX;
    const float* content_b = content + (size_t)(bg0 + gb) * TBe;
    const float* mu  = mub  + (size_t)(bg0 + gb) * CDIM;
    const float* isd = isdb + (size_t)(bg0 + gb) * CDIM;
    float* out_b = out + (size_t)(bg0 + gb) * TBe;

    const int t = threadIdx.x;
    const int lane = t & 63, wv = t >> 6;       // 4 waves
    const int wr = wv >> 1, wc = wv & 1;        // 2 x 2
    const int l31 = lane & 31, h = lane >> 5;

    int c_t, n_t;
    if (swz) {          // gridDim.x % 8 == 0
        const int chunk = (int)gridDim.x >> 3;
        const int id = (blockIdx.x & 7) * chunk + (blockIdx.x >> 3);
        c_t = id & 3;                           // CDIM/128 == 4
        n_t = id >> 2;
    } else {
        c_t = blockIdx.x & 3;
        n_t = blockIdx.x >> 2;
    }
    const int c0  = c_t * 128;
    const int nl0 = n_t * 128;

    __shared__ short AS[2][128][128];           // 2 x 32 KB

    f32x16 am[2][2] = {};
    f32x16 aq[2][2] = {};

    // staging: 32 x 1KB chunks, 8 per wave; chunk = 4 LDS rows x 256B;
    // lane -> row r0+(l>>4), phys slot l&15; logical c = (l&15)^(r&15):
    // c<8 -> H row (c0+r) k-seg c, else S row (nl0+r) k-seg c-8.
    const int lr = lane >> 4, lq = lane & 15;

    #define PV_STAGE(BUF, KB)                                                  \
    {                                                                          \
        _Pragma("unroll")                                                      \
        for (int ch = 0; ch < 8; ch++) {                                       \
            const int r0 = wv*32 + ch*4;                                       \
            const int r  = r0 + lr;                                            \
            const int c  = lq ^ (r & 15);                                      \
            const u16* gp = (c < 8)                                            \
                ? &Hb[(size_t)(c0  + r) * NPIX + (KB) + c*8]                   \
                : &Sb[(size_t)(nl0 + r) * NPIX + (KB) + (c-8)*8];              \
            GLD16(gp, &AS[BUF][r0][0]);                                        \
        }                                                                      \
    }

    PV_STAGE(0, 0);
    __syncthreads();

    int buf = 0;
    for (int kb = 0; kb < NPIX; kb += 64) {
        if (kb + 64 < NPIX) PV_STAGE(buf ^ 1, kb + 64);
        #pragma unroll
        for (int ks = 0; ks < 4; ks++) {
            const int sg = ks*2 + h;            // logical k-seg 0..7
            bf16x8 a[2], a2[2], b[2];
            #pragma unroll
            for (int i = 0; i < 2; i++) {
                const int q = wr*64 + i*32 + l31;          // H row
                a[i]  = *(const bf16x8*)&AS[buf][q][(sg ^ (q & 15)) * 8];
                a2[i] = sq_bf16x8(a[i]);
            }
            #pragma unroll
            for (int j = 0; j < 2; j++) {
                const int q = wc*64 + j*32 + l31;          // S row
                b[j] = *(const bf16x8*)&AS[buf][q][((8 + sg) ^ (q & 15)) * 8];
            }
            #pragma unroll
            for (int i = 0; i < 2; i++)
                #pragma unroll
                for (int j = 0; j < 2; j++) {
                    am[i][j] = MFMA32(a[i],  b[j], am[i][j], 0, 0, 0);
                    aq[i][j] = MFMA32(a2[i], b[j], aq[i][j], 0, 0, 0);
                }
        }
        __syncthreads();
        buf ^= 1;
    }
    #undef PV_STAGE

    // C layout (32x32): col = lane&31 (n), row = (reg&3) + 8*(reg>>2) + 4*h (c)
    #pragma unroll
    for (int j = 0; j < 2; j++) {
        const int n = strip_base + nl0 + wc*64 + j*32 + l31;
        const float inv = 1.f / (rs[n] + EPSN);
        #pragma unroll
        for (int i = 0; i < 2; i++) {
            #pragma unroll
            for (int qd = 0; qd < 4; qd++) {
                const int cb = c0 + wr*64 + i*32 + 8*qd + 4*h;
                float4 mu4 = *(const float4*)&mu[cb];
                float4 is4 = *(const float4*)&isd[cb];
                const float muA[4] = { mu4.x, mu4.y, mu4.z, mu4.w };
                const float isA[4] = { is4.x, is4.y, is4.z, is4.w };
                #pragma unroll
                for (int r2 = 0; r2 < 4; r2++) {
                    const int reg = qd*4 + r2;
                    float mean = am[i][j][reg] * inv;
                    float msq  = aq[i][j][reg] * inv;
                    float sd   = sqrtf(fmaxf(msq - mean*mean, 0.f));
                    float cv   = content_b[(size_t)(cb + r2) * NPIX + n];
                    out_b[(size_t)(cb + r2) * NPIX + n] = sd * (cv - muA[r2]) * isA[r2] + mean;
                }
            }
        }
    }
}

// ---------------------------------------------------------------------------
// content_stats: per (b,c) mean and 1/std (unbiased var, +1e-5), fp32 input
// ---------------------------------------------------------------------------
__global__ __launch_bounds__(256) void content_stats(const float* __restrict__ x,
    float* __restrict__ mu, float* __restrict__ isd)
{
    const int bc = blockIdx.x;
    const int tid = threadIdx.x;
    const float* row = x + (size_t)bc * NPIX;
    float s = 0.f, s2 = 0.f;
    for (int i = tid * 4; i < NPIX; i += 256 * 4) {
        float4 v = *(const float4*)&row[i];
        s  += v.x + v.y + v.z + v.w;
        s2 += v.x*v.x + v.y*v.y + v.z*v.z + v.w*v.w;
    }
    __shared__ float r1[256], r2[256];
    r1[tid] = s; r2[tid] = s2; __syncthreads();
    for (int st = 128; st; st >>= 1) {
        if (tid < st) { r1[tid] += r1[tid+st]; r2[tid] += r2[tid+st]; }
        __syncthreads();
    }
    if (tid == 0) {
        float m = r1[0] / NPIX;
        float var = (r2[0] - (float)NPIX * m * m) / (float)(NPIX - 1);
        mu[bc]  = m;
        isd[bc] = rsqrtf(var + 1e-5f);
    }
}

// ---------------------------------------------------------------------------
extern "C" void kernel_launch(void* const* d_in, const int* in_sizes, int n_in,
                              void* d_out, int out_size, void* d_ws, size_t ws_size,
                              hipStream_t stream)
{
    const float* content     = (const float*)d_in[0];
    const float* style       = (const float*)d_in[1];
    const float* content_key = (const float*)d_in[2];
    const float* style_key   = (const float*)d_in[3];
    const float* Wf  = (const float*)d_in[4];
    const float* bf_ = (const float*)d_in[5];
    const float* Wg  = (const float*)d_in[6];
    const float* bg  = (const float*)d_in[7];
    const float* Wh  = (const float*)d_in[8];
    const float* bh  = (const float*)d_in[9];
    float* out = (float*)d_out;

    const size_t TB = (size_t)CDIM * NPIX;   // elems per batch-tensor
    const size_t tail_bytes = (3 * (size_t)B_SZ * NPIX + 2 * (size_t)B_SZ * CDIM) * 4 + 256;

    // choose (nb, ns): bytes = nb*(6*TB + NPIX*ns)*2 + tail
    int nb = 1, ns = 512;
    {
        const int nbc[5] = {4, 2, 4, 2, 1};
        const int nsc[5] = {4096, 4096, 2048, 2048, 4096};
        bool found = false;
        for (int i = 0; i < 5; i++) {
            size_t need = (size_t)nbc[i] * (6 * TB + (size_t)NPIX * nsc[i]) * 2 + tail_bytes;
            if (need <= ws_size) { nb = nbc[i]; ns = nsc[i]; found = true; break; }
        }
        if (!found) {
            nb = 1;
            for (int cand = 2048; cand >= 512; cand >>= 1) {
                size_t need = (6 * TB + (size_t)NPIX * cand) * 2 + tail_bytes;
                if (need <= ws_size) { ns = cand; break; }
            }
        }
    }
    const size_t s_stride = (size_t)NPIX * ns;   // elems per batch S strip

    u16* FT  = (u16*)d_ws;                   // nb x [NPIX][CDIM]
    u16* GT  = FT + (size_t)nb * TB;
    u16* Hb  = GT + (size_t)nb * TB;         // nb x [CDIM][NPIX]
    u16* XT  = Hb + (size_t)nb * TB;         // nb*3 x [NPIX][CDIM]
    u16* Sb  = XT + (size_t)nb * 3 * TB;     // nb x [ns][NPIX]
    float* Fn  = (float*)(Sb + (size_t)nb * s_stride);
    float* Gn  = Fn + (size_t)B_SZ * NPIX;
    float* rsb = Gn + (size_t)B_SZ * NPIX;
    float* mu  = rsb + (size_t)B_SZ * NPIX;
    float* isd = mu + (size_t)B_SZ * CDIM;

    content_stats<<<B_SZ * CDIM, 256, 0, stream>>>(content, mu, isd);

    const int sg_swz = ((ns / 128) % 8 == 0) ? 1 : 0;
    const int sg_blocks = (NPIX / 128) * (ns / 128);
    const int pv_blocks = (CDIM / 128) * (ns / 128);
    const int pv_swz = (pv_blocks % 8 == 0) ? 1 : 0;

    for (int bg0 = 0; bg0 < B_SZ; bg0 += nb) {
        const int g = (bg0 + nb <= B_SZ) ? nb : (B_SZ - bg0);

        transpose3b<<<dim3(NPIX/64, CDIM/64, 3*g), 256, 0, stream>>>(
                content_key, style_key, style, XT, bg0);

        conv3b<<<dim3(NPIX/64, CDIM/64, 3*g), 256, 0, stream>>>(
                XT, Wf, Wg, Wh, bf_, bg, bh, FT, GT, Hb);

        norm2b<<<dim3(NPIX/256, 2*g), 256, 0, stream>>>(FT, GT, Fn, Gn, rsb);

        for (int s0 = 0; s0 < NPIX; s0 += ns) {
            s_gemm128<<<dim3(sg_blocks, g), 256, 0, stream>>>(FT, GT, Fn, Gn,
                    Sb, rsb, s0, sg_swz, s_stride);
            pv128<<<dim3(pv_blocks, g), 256, 0, stream>>>(Hb, Sb, rsb,
                    content, mu, isd, out, s0, bg0, s_stride, pv_swz);
        }
    }
}

// Round 18
// 378.072 us; speedup vs baseline: 1.6317x; 1.0250x over previous
//
#include <hip/hip_runtime.h>
#include <hip/hip_bf16.h>
#include <math.h>

#define B_SZ 4
#define CDIM 512
#define NPIX 4096
#define EPSN 1e-5f

typedef unsigned short u16;
typedef __attribute__((ext_vector_type(8))) short bf16x8;
typedef __attribute__((ext_vector_type(4))) float f32x4;
typedef __attribute__((ext_vector_type(16))) float f32x16;

#define MFMA_BF16 __builtin_amdgcn_mfma_f32_16x16x32_bf16
#define MFMA32    __builtin_amdgcn_mfma_f32_32x32x16_bf16

// async global->LDS DMA, 16B per lane; LDS dest = wave-uniform base + lane*16
#define GLD16(gp, lp) __builtin_amdgcn_global_load_lds( \
    (const __attribute__((address_space(1))) void*)(gp), \
    (__attribute__((address_space(3))) void*)(lp), 16, 0, 0)

static __device__ __forceinline__ float bf2f(u16 u) {
    return __uint_as_float(((unsigned)u) << 16);
}
static __device__ __forceinline__ u16 f2bf(float f) {
    unsigned u = __float_as_uint(f);
    unsigned r = (u + 0x7FFFu + ((u >> 16) & 1u)) >> 16;
    return (u16)r;
}
// packed square of a bf16x8 fragment, truncating round; v_perm repack
static __device__ __forceinline__ bf16x8 sq_bf16x8(bf16x8 a) {
    union { bf16x8 v; unsigned w[4]; } in, out;
    in.v = a;
    #pragma unroll
    for (int k = 0; k < 4; k++) {
        unsigned wl = in.w[k] << 16;
        unsigned wh = in.w[k] & 0xFFFF0000u;
        float sl = __uint_as_float(wl); sl *= sl;
        float sh = __uint_as_float(wh); sh *= sh;
        out.w[k] = __builtin_amdgcn_perm(__float_as_uint(sh), __float_as_uint(sl),
                                         0x07060302u);
    }
    return out.v;
}

// ---------------------------------------------------------------------------
// transpose3b: z = gb*3 + which; source fp32 [CDIM][NPIX] (global batch
// bg0+gb) -> XT slab entry z, bf16 [NPIX][CDIM].
// ---------------------------------------------------------------------------
__global__ __launch_bounds__(256) void transpose3b(const float* __restrict__ X0,
    const float* __restrict__ X1, const float* __restrict__ X2,
    u16* __restrict__ XTbase, int bg0)
{
    const int z = blockIdx.z;
    const int gb = z / 3, which = z % 3;
    const size_t TBe = (size_t)CDIM * NPIX;
    const float* X = (which == 0 ? X0 : which == 1 ? X1 : X2) + (size_t)(bg0 + gb) * TBe;
    u16* XT = XTbase + (size_t)z * TBe;

    __shared__ float T[64][65];
    const int t = threadIdx.x;
    const int n0 = blockIdx.x * 64, c0 = blockIdx.y * 64;
    #pragma unroll
    for (int p = 0; p < 4; p++) {
        int c_l = (t >> 4) + p * 16;
        int n_l = (t & 15) * 4;
        float4 v = *(const float4*)&X[(size_t)(c0 + c_l) * NPIX + n0 + n_l];
        T[c_l][n_l+0] = v.x; T[c_l][n_l+1] = v.y; T[c_l][n_l+2] = v.z; T[c_l][n_l+3] = v.w;
    }
    __syncthreads();
    #pragma unroll
    for (int p = 0; p < 4; p++) {
        int n_l = t >> 2;
        int cs  = (t & 3) * 4 + p * 16;
        ushort4 r;
        r.x = f2bf(T[cs+0][n_l]); r.y = f2bf(T[cs+1][n_l]);
        r.z = f2bf(T[cs+2][n_l]); r.w = f2bf(T[cs+3][n_l]);
        *(ushort4*)&XT[(size_t)(n0 + n_l) * CDIM + c0 + cs] = r;
    }
}

// ---------------------------------------------------------------------------
// conv3b: z = gb*3 + which. D[o][n] = bias[o] + sum_c W[o][c]*XT[n][c].
// which<2: store D^T to (FT|GT)+gb*TB ([n][CDIM]); which==2: Hb+gb*TB.
// ---------------------------------------------------------------------------
__global__ __launch_bounds__(256) void conv3b(const u16* __restrict__ XTbase,
    const float* __restrict__ W0, const float* __restrict__ W1, const float* __restrict__ W2,
    const float* __restrict__ b0, const float* __restrict__ b1, const float* __restrict__ b2,
    u16* __restrict__ FTb, u16* __restrict__ GTb, u16* __restrict__ Hbb)
{
    const int z = blockIdx.z;
    const int gb = z / 3, which = z % 3;
    const size_t TBe = (size_t)CDIM * NPIX;
    const u16* XT = XTbase + (size_t)z * TBe;
    const float* W = which == 0 ? W0 : which == 1 ? W1 : W2;
    const float* bias = which == 0 ? b0 : which == 1 ? b1 : b2;

    const int t = threadIdx.x;
    const int lane = t & 63, wv = t >> 6;
    const int wr = wv >> 1, wc = wv & 1;
    const int n0 = blockIdx.x * 64;
    const int o0 = blockIdx.y * 64;
    const int g = lane >> 4, li = lane & 15;

    __shared__ short Aw[64][40];
    __shared__ short Bx[64][40];

    f32x4 acc[2][2] = {};
    const int srow = t >> 2, sseg = (t & 3) * 8;

    float4 w0 = *(const float4*)&W[(size_t)(o0 + srow) * CDIM + sseg];
    float4 w1 = *(const float4*)&W[(size_t)(o0 + srow) * CDIM + sseg + 4];
    bf16x8 bv = *(const bf16x8*)&XT[(size_t)(n0 + srow) * CDIM + sseg];

    for (int kb = 0; kb < CDIM; kb += 32) {
        bf16x8 wa;
        wa[0] = (short)f2bf(w0.x); wa[1] = (short)f2bf(w0.y);
        wa[2] = (short)f2bf(w0.z); wa[3] = (short)f2bf(w0.w);
        wa[4] = (short)f2bf(w1.x); wa[5] = (short)f2bf(w1.y);
        wa[6] = (short)f2bf(w1.z); wa[7] = (short)f2bf(w1.w);
        __syncthreads();
        *(bf16x8*)&Aw[srow][sseg] = wa;
        *(bf16x8*)&Bx[srow][sseg] = bv;
        if (kb + 32 < CDIM) {
            w0 = *(const float4*)&W[(size_t)(o0 + srow) * CDIM + kb + 32 + sseg];
            w1 = *(const float4*)&W[(size_t)(o0 + srow) * CDIM + kb + 32 + sseg + 4];
            bv = *(const bf16x8*)&XT[(size_t)(n0 + srow) * CDIM + kb + 32 + sseg];
        }
        __syncthreads();
        bf16x8 a[2], b[2];
        #pragma unroll
        for (int i = 0; i < 2; i++) a[i] = *(const bf16x8*)&Aw[wr*32 + i*16 + li][g*8];
        #pragma unroll
        for (int j = 0; j < 2; j++) b[j] = *(const bf16x8*)&Bx[wc*32 + j*16 + li][g*8];
        #pragma unroll
        for (int i = 0; i < 2; i++)
            #pragma unroll
            for (int j = 0; j < 2; j++)
                acc[i][j] = MFMA_BF16(a[i], b[j], acc[i][j], 0, 0, 0);
    }

    #pragma unroll
    for (int i = 0; i < 2; i++) {
        const int orow = o0 + wr*32 + i*16 + 4*g;
        float4 bs = *(const float4*)&bias[orow];
        #pragma unroll
        for (int j = 0; j < 2; j++) {
            const int ncol = n0 + wc*32 + j*16 + li;
            if (which < 2) {
                u16* Y = (which == 0 ? FTb : GTb) + (size_t)gb * TBe;
                ushort4 r;
                r.x = f2bf(acc[i][j][0] + bs.x);
                r.y = f2bf(acc[i][j][1] + bs.y);
                r.z = f2bf(acc[i][j][2] + bs.z);
                r.w = f2bf(acc[i][j][3] + bs.w);
                *(ushort4*)&Y[(size_t)ncol * CDIM + orow] = r;
            } else {
                u16* Y2 = Hbb + (size_t)gb * TBe;
                const float bb[4] = { bs.x, bs.y, bs.z, bs.w };
                #pragma unroll
                for (int r = 0; r < 4; r++)
                    Y2[(size_t)(orow + r) * NPIX + ncol] = f2bf(acc[i][j][r] + bb[r]);
            }
        }
    }
}

// ---------------------------------------------------------------------------
// norm2b: blockIdx.y = gb*2 + z. z=0: Fn[gb][n], rs[gb][n]=0 ; z=1: Gn[gb][n]
// ---------------------------------------------------------------------------
__global__ __launch_bounds__(256) void norm2b(const u16* __restrict__ FT,
    const u16* __restrict__ GT, float* __restrict__ Fn, float* __restrict__ Gn,
    float* __restrict__ rs)
{
    const int gb = blockIdx.y >> 1, z = blockIdx.y & 1;
    const size_t TBe = (size_t)CDIM * NPIX;
    const int n = blockIdx.x * 256 + threadIdx.x;
    const u16* row = ((z ? GT : FT) + (size_t)gb * TBe) + (size_t)n * CDIM;
    float s = 0.f;
    for (int c = 0; c < CDIM; c += 8) {
        bf16x8 v = *(const bf16x8*)&row[c];
        #pragma unroll
        for (int e = 0; e < 8; e++) { float f = bf2f((u16)v[e]); s += f * f; }
    }
    ((z ? Gn : Fn) + (size_t)gb * NPIX)[n] = sqrtf(s);
    if (!z) rs[(size_t)gb * NPIX + n] = 0.f;
}

// ---------------------------------------------------------------------------
// s_gemm128: S[nl][m] = bf16(relu(dot/((Fn+e)(Gn+e)) + 1)), + rowsum atomics.
// 128x128 tile, 4 waves (2x2 of 64x64), K-step 32, gld_lds DMA staging with
// source-side swizzle. T4 counted-vmcnt sync: {issue(t+1); vmcnt(4);
// raw barrier; compute(t); raw barrier} — next tile's 4 DMAs/wave stay in
// flight across the barriers (no drain), the r17 ~950TF ceiling breaker.
// ---------------------------------------------------------------------------
__global__ __launch_bounds__(256) void s_gemm128(const u16* __restrict__ FTb,
    const u16* __restrict__ GTb, const float* __restrict__ Fnb, const float* __restrict__ Gnb,
    u16* __restrict__ Sbase, float* __restrict__ rsb, int strip_base, int swz,
    size_t s_stride)
{
    const int gb = blockIdx.y;
    const size_t TBe = (size_t)CDIM * NPIX;
    const u16* FT = FTb + (size_t)gb * TBe;
    const u16* GT = GTb + (size_t)gb * TBe;
    const float* Fn = Fnb + (size_t)gb * NPIX;
    const float* Gn = Gnb + (size_t)gb * NPIX;
    u16* S = Sbase + (size_t)gb * s_stride;
    float* rs = rsb + (size_t)gb * NPIX;

    const int t = threadIdx.x;
    const int lane = t & 63, wv = t >> 6;
    const int wr = wv >> 1, wc = wv & 1;

    int mm, nn;
    if (swz) {            // (ns/128) % 8 == 0
        const int xk = blockIdx.x & 7, q = blockIdx.x >> 3;
        mm = q & 31;                      // NPIX/128 == 32
        nn = (q >> 5) * 8 + xk;
    } else {
        mm = blockIdx.x & 31;
        nn = blockIdx.x >> 5;
    }
    const int m0  = mm * 128;
    const int nl0 = nn * 128;
    const int ng0 = strip_base + nl0;
    const int g = lane >> 4, li = lane & 15;

    __shared__ short Cs[2][128][64];   // 32 KB total

    f32x4 acc[4][4] = {};

    const int lr = lane >> 3, lq = lane & 7;

    #define SG_STAGE(BUF, KB)                                                  \
    {                                                                          \
        _Pragma("unroll")                                                      \
        for (int ch = 0; ch < 4; ch++) {                                       \
            const int r0 = wv*32 + ch*8;                                       \
            const int r  = r0 + lr;                                            \
            const int c  = lq ^ (r & 7);                                       \
            const u16* gp = (c < 4)                                            \
                ? &FT[(size_t)(ng0 + r) * CDIM + (KB) + c*8]                   \
                : &GT[(size_t)(m0  + r) * CDIM + (KB) + (c-4)*8];              \
            GLD16(gp, &Cs[BUF][r0][0]);                                        \
        }                                                                      \
    }

    SG_STAGE(0, 0);

    int buf = 0;
    for (int kb = 0; kb < CDIM; kb += 32) {
        if (kb + 32 < CDIM) {
            SG_STAGE(buf ^ 1, kb + 32);
            asm volatile("s_waitcnt vmcnt(4)" ::: "memory");   // tile t landed
        } else {
            asm volatile("s_waitcnt vmcnt(0)" ::: "memory");
        }
        __builtin_amdgcn_s_barrier();
        bf16x8 a[4], b[4];
        #pragma unroll
        for (int i = 0; i < 4; i++) {
            const int row = wr*64 + i*16 + li;
            a[i] = *(const bf16x8*)&Cs[buf][row][(g ^ (row & 7)) * 8];
        }
        #pragma unroll
        for (int j = 0; j < 4; j++) {
            const int row = wc*64 + j*16 + li;
            b[j] = *(const bf16x8*)&Cs[buf][row][((4 + g) ^ (row & 7)) * 8];
        }
        #pragma unroll
        for (int i = 0; i < 4; i++)
            #pragma unroll
            for (int j = 0; j < 4; j++)
                acc[i][j] = MFMA_BF16(a[i], b[j], acc[i][j], 0, 0, 0);
        __builtin_amdgcn_s_barrier();      // reads done -> next issue may reuse buf
        buf ^= 1;
    }
    #undef SG_STAGE

    float gi[4];
    #pragma unroll
    for (int j = 0; j < 4; j++) gi[j] = 1.f / (Gn[m0 + wc*64 + j*16 + li] + EPSN);
    #pragma unroll
    for (int i = 0; i < 4; i++) {
        const int nl = nl0 + wr*64 + i*16 + 4*g;
        float4 fn4 = *(const float4*)&Fn[strip_base + nl];
        const float fi4[4] = { 1.f/(fn4.x + EPSN), 1.f/(fn4.y + EPSN),
                               1.f/(fn4.z + EPSN), 1.f/(fn4.w + EPSN) };
        float ps[4] = {0.f, 0.f, 0.f, 0.f};
        #pragma unroll
        for (int j = 0; j < 4; j++) {
            const int m = m0 + wc*64 + j*16 + li;
            #pragma unroll
            for (int r = 0; r < 4; r++) {
                float v = fmaxf(acc[i][j][r] * fi4[r] * gi[j] + 1.f, 0.f);
                u16 hv = f2bf(v);
                S[(size_t)(nl + r) * NPIX + m] = hv;
                ps[r] += bf2f(hv);
            }
        }
        #pragma unroll
        for (int r = 0; r < 4; r++) {
            float p = ps[r];
            p += __shfl_xor(p, 1);
            p += __shfl_xor(p, 2);
            p += __shfl_xor(p, 4);
            p += __shfl_xor(p, 8);
            if (li == 0) atomicAdd(&rs[strip_base + nl + r], p);
        }
    }
}

// ---------------------------------------------------------------------------
// pv128: mean/msq via MFMA 32x32x16 (dual chains, H^2 in-register).
// Tile 128c x 128n, 4 waves of 64x64. T4 counted-vmcnt sync: next tile's
// 8 DMAs/wave stay in flight across raw barriers instead of the
// __syncthreads vmcnt(0) drain that capped r17 at ~950 TF.
// LDS 2x32KB, 16-slot XOR involution (source-side + read), 2 blocks/CU.
// ---------------------------------------------------------------------------
__global__ __launch_bounds__(256, 2) void pv128(const u16* __restrict__ Hbb,
    const u16* __restrict__ Sbase, const float* __restrict__ rsb,
    const float* __restrict__ content, const float* __restrict__ mub,
    const float* __restrict__ isdb, float* __restrict__ out, int strip_base,
    int bg0, size_t s_stride, int swz)
{
    const int gb = blockIdx.y;
    const size_t TBe = (size_t)CDIM * NPIX;
    const u16* Hb = Hbb + (size_t)gb * TBe;
    const u16* Sb = Sbase + (size_t)gb * s_stride;
    const float* rs = rsb + (size_t)gb * NPIX;
    const float* content_b = content + (size_t)(bg0 + gb) * TBe;
    const float* mu  = mub  + (size_t)(bg0 + gb) * CDIM;
    const float* isd = isdb + (size_t)(bg0 + gb) * CDIM;
    float* out_b = out + (size_t)(bg0 + gb) * TBe;

    const int t = threadIdx.x;
    const int lane = t & 63, wv = t >> 6;       // 4 waves
    const int wr = wv >> 1, wc = wv & 1;        // 2 x 2
    const int l31 = lane & 31, h = lane >> 5;

    int c_t, n_t;
    if (swz) {          // gridDim.x % 8 == 0
        const int chunk = (int)gridDim.x >> 3;
        const int id = (blockIdx.x & 7) * chunk + (blockIdx.x >> 3);
        c_t = id & 3;                           // CDIM/128 == 4
        n_t = id >> 2;
    } else {
        c_t = blockIdx.x & 3;
        n_t = blockIdx.x >> 2;
    }
    const int c0  = c_t * 128;
    const int nl0 = n_t * 128;

    __shared__ short AS[2][128][128];           // 2 x 32 KB

    f32x16 am[2][2] = {};
    f32x16 aq[2][2] = {};

    const int lr = lane >> 4, lq = lane & 15;

    #define PV_STAGE(BUF, KB)                                                  \
    {                                                                          \
        _Pragma("unroll")                                                      \
        for (int ch = 0; ch < 8; ch++) {                                       \
            const int r0 = wv*32 + ch*4;                                       \
            const int r  = r0 + lr;                                            \
            const int c  = lq ^ (r & 15);                                      \
            const u16* gp = (c < 8)                                            \
                ? &Hb[(size_t)(c0  + r) * NPIX + (KB) + c*8]                   \
                : &Sb[(size_t)(nl0 + r) * NPIX + (KB) + (c-8)*8];              \
            GLD16(gp, &AS[BUF][r0][0]);                                        \
        }                                                                      \
    }

    PV_STAGE(0, 0);

    int buf = 0;
    for (int kb = 0; kb < NPIX; kb += 64) {
        if (kb + 64 < NPIX) {
            PV_STAGE(buf ^ 1, kb + 64);
            asm volatile("s_waitcnt vmcnt(8)" ::: "memory");   // tile t landed
        } else {
            asm volatile("s_waitcnt vmcnt(0)" ::: "memory");
        }
        __builtin_amdgcn_s_barrier();
        #pragma unroll
        for (int ks = 0; ks < 4; ks++) {
            const int sg = ks*2 + h;            // logical k-seg 0..7
            bf16x8 a[2], a2[2], b[2];
            #pragma unroll
            for (int i = 0; i < 2; i++) {
                const int q = wr*64 + i*32 + l31;          // H row
                a[i]  = *(const bf16x8*)&AS[buf][q][(sg ^ (q & 15)) * 8];
                a2[i] = sq_bf16x8(a[i]);
            }
            #pragma unroll
            for (int j = 0; j < 2; j++) {
                const int q = wc*64 + j*32 + l31;          // S row
                b[j] = *(const bf16x8*)&AS[buf][q][((8 + sg) ^ (q & 15)) * 8];
            }
            #pragma unroll
            for (int i = 0; i < 2; i++)
                #pragma unroll
                for (int j = 0; j < 2; j++) {
                    am[i][j] = MFMA32(a[i],  b[j], am[i][j], 0, 0, 0);
                    aq[i][j] = MFMA32(a2[i], b[j], aq[i][j], 0, 0, 0);
                }
        }
        __builtin_amdgcn_s_barrier();      // reads done -> next issue may reuse buf
        buf ^= 1;
    }
    #undef PV_STAGE

    // C layout (32x32): col = lane&31 (n), row = (reg&3) + 8*(reg>>2) + 4*h (c)
    #pragma unroll
    for (int j = 0; j < 2; j++) {
        const int n = strip_base + nl0 + wc*64 + j*32 + l31;
        const float inv = 1.f / (rs[n] + EPSN);
        #pragma unroll
        for (int i = 0; i < 2; i++) {
            #pragma unroll
            for (int qd = 0; qd < 4; qd++) {
                const int cb = c0 + wr*64 + i*32 + 8*qd + 4*h;
                float4 mu4 = *(const float4*)&mu[cb];
                float4 is4 = *(const float4*)&isd[cb];
                const float muA[4] = { mu4.x, mu4.y, mu4.z, mu4.w };
                const float isA[4] = { is4.x, is4.y, is4.z, is4.w };
                #pragma unroll
                for (int r2 = 0; r2 < 4; r2++) {
                    const int reg = qd*4 + r2;
                    float mean = am[i][j][reg] * inv;
                    float msq  = aq[i][j][reg] * inv;
                    float sd   = sqrtf(fmaxf(msq - mean*mean, 0.f));
                    float cv   = content_b[(size_t)(cb + r2) * NPIX + n];
                    out_b[(size_t)(cb + r2) * NPIX + n] = sd * (cv - muA[r2]) * isA[r2] + mean;
                }
            }
        }
    }
}

// ---------------------------------------------------------------------------
// content_stats: per (b,c) mean and 1/std (unbiased var, +1e-5), fp32 input
// ---------------------------------------------------------------------------
__global__ __launch_bounds__(256) void content_stats(const float* __restrict__ x,
    float* __restrict__ mu, float* __restrict__ isd)
{
    const int bc = blockIdx.x;
    const int tid = threadIdx.x;
    const float* row = x + (size_t)bc * NPIX;
    float s = 0.f, s2 = 0.f;
    for (int i = tid * 4; i < NPIX; i += 256 * 4) {
        float4 v = *(const float4*)&row[i];
        s  += v.x + v.y + v.z + v.w;
        s2 += v.x*v.x + v.y*v.y + v.z*v.z + v.w*v.w;
    }
    __shared__ float r1[256], r2[256];
    r1[tid] = s; r2[tid] = s2; __syncthreads();
    for (int st = 128; st; st >>= 1) {
        if (tid < st) { r1[tid] += r1[tid+st]; r2[tid] += r2[tid+st]; }
        __syncthreads();
    }
    if (tid == 0) {
        float m = r1[0] / NPIX;
        float var = (r2[0] - (float)NPIX * m * m) / (float)(NPIX - 1);
        mu[bc]  = m;
        isd[bc] = rsqrtf(var + 1e-5f);
    }
}

// ---------------------------------------------------------------------------
extern "C" void kernel_launch(void* const* d_in, const int* in_sizes, int n_in,
                              void* d_out, int out_size, void* d_ws, size_t ws_size,
                              hipStream_t stream)
{
    const float* content     = (const float*)d_in[0];
    const float* style       = (const float*)d_in[1];
    const float* content_key = (const float*)d_in[2];
    const float* style_key   = (const float*)d_in[3];
    const float* Wf  = (const float*)d_in[4];
    const float* bf_ = (const float*)d_in[5];
    const float* Wg  = (const float*)d_in[6];
    const float* bg  = (const float*)d_in[7];
    const float* Wh  = (const float*)d_in[8];
    const float* bh  = (const float*)d_in[9];
    float* out = (float*)d_out;

    const size_t TB = (size_t)CDIM * NPIX;   // elems per batch-tensor
    const size_t tail_bytes = (3 * (size_t)B_SZ * NPIX + 2 * (size_t)B_SZ * CDIM) * 4 + 256;

    // choose (nb, ns): bytes = nb*(6*TB + NPIX*ns)*2 + tail
    int nb = 1, ns = 512;
    {
        const int nbc[5] = {4, 2, 4, 2, 1};
        const int nsc[5] = {4096, 4096, 2048, 2048, 4096};
        bool found = false;
        for (int i = 0; i < 5; i++) {
            size_t need = (size_t)nbc[i] * (6 * TB + (size_t)NPIX * nsc[i]) * 2 + tail_bytes;
            if (need <= ws_size) { nb = nbc[i]; ns = nsc[i]; found = true; break; }
        }
        if (!found) {
            nb = 1;
            for (int cand = 2048; cand >= 512; cand >>= 1) {
                size_t need = (6 * TB + (size_t)NPIX * cand) * 2 + tail_bytes;
                if (need <= ws_size) { ns = cand; break; }
            }
        }
    }
    const size_t s_stride = (size_t)NPIX * ns;   // elems per batch S strip

    u16* FT  = (u16*)d_ws;                   // nb x [NPIX][CDIM]
    u16* GT  = FT + (size_t)nb * TB;
    u16* Hb  = GT + (size_t)nb * TB;         // nb x [CDIM][NPIX]
    u16* XT  = Hb + (size_t)nb * TB;         // nb*3 x [NPIX][CDIM]
    u16* Sb  = XT + (size_t)nb * 3 * TB;     // nb x [ns][NPIX]
    float* Fn  = (float*)(Sb + (size_t)nb * s_stride);
    float* Gn  = Fn + (size_t)B_SZ * NPIX;
    float* rsb = Gn + (size_t)B_SZ * NPIX;
    float* mu  = rsb + (size_t)B_SZ * NPIX;
    float* isd = mu + (size_t)B_SZ * CDIM;

    content_stats<<<B_SZ * CDIM, 256, 0, stream>>>(content, mu, isd);

    const int sg_swz = ((ns / 128) % 8 == 0) ? 1 : 0;
    const int sg_blocks = (NPIX / 128) * (ns / 128);
    const int pv_blocks = (CDIM / 128) * (ns / 128);
    const int pv_swz = (pv_blocks % 8 == 0) ? 1 : 0;

    for (int bg0 = 0; bg0 < B_SZ; bg0 += nb) {
        const int g = (bg0 + nb <= B_SZ) ? nb : (B_SZ - bg0);

        transpose3b<<<dim3(NPIX/64, CDIM/64, 3*g), 256, 0, stream>>>(
                content_key, style_key, style, XT, bg0);

        conv3b<<<dim3(NPIX/64, CDIM/64, 3*g), 256, 0, stream>>>(
                XT, Wf, Wg, Wh, bf_, bg, bh, FT, GT, Hb);

        norm2b<<<dim3(NPIX/256, 2*g), 256, 0, stream>>>(FT, GT, Fn, Gn, rsb);

        for (int s0 = 0; s0 < NPIX; s0 += ns) {
            s_gemm128<<<dim3(sg_blocks, g), 256, 0, stream>>>(FT, GT, Fn, Gn,
                    Sb, rsb, s0, sg_swz, s_stride);
            pv128<<<dim3(pv_blocks, g), 256, 0, stream>>>(Hb, Sb, rsb,
                    content, mu, isd, out, s0, bg0, s_stride, pv_swz);
        }
    }
}